// Round 4
// baseline (770.924 us; speedup 1.0000x reference)
//
#include <hip/hip_runtime.h>
#include <hip/hip_bf16.h>

// GCN 3-layer. CSR aggregation built via dst-buckets (no write amplification),
// bf16 gather table:
//   hs(bf16) = (X@W) * d_inv[row]   (fp32 GEMM, bf16 RNE epilogue, stride 64)
//   out_i = act(d_inv[i]*(hs_i + sum_{e:dst=i} hs[src_e]) + b)
//     (one wave/node; 8 edges in flight x 8 lanes x 16B, fp32 accumulate)

constexpr int BLK = 256;
constexpr int SB  = 7;                 // bucket = 128 nodes

__device__ inline unsigned short bf_rne(float f) {
    unsigned int u = __float_as_uint(f);
    unsigned int r = (u + 0x7fffu + ((u >> 16) & 1u)) >> 16;
    return (unsigned short)r;
}
__device__ inline unsigned int pk(unsigned short lo, unsigned short hi) {
    return (unsigned int)lo | ((unsigned int)hi << 16);
}

// ---------- utility ----------
__global__ void zero_int(int* p, int n) {
    int i = blockIdx.x * BLK + threadIdx.x;
    if (i < n) p[i] = 0;
}

__global__ void hist_dst(const int* __restrict__ dst, int* __restrict__ cnt, int E) {
    int e = blockIdx.x * BLK + threadIdx.x;
    if (e < E) atomicAdd(&cnt[dst[e]], 1);
}

__global__ void dinv_from_cnt(const int* __restrict__ cnt, float* __restrict__ dinv, int n) {
    int i = blockIdx.x * BLK + threadIdx.x;
    if (i < n) dinv[i] = rsqrtf((float)cnt[i] + 1.0f);   // +1 self-loop
}

// ---------- exclusive scan (3 kernels, chunk = 1024 elements) ----------
__global__ void scan_chunks(const int* __restrict__ cnt, int* __restrict__ excl,
                            int* __restrict__ csums, int n) {
    __shared__ int sh[256];
    int t = threadIdx.x;
    int base = blockIdx.x * 1024;
    int v[4]; int s = 0;
#pragma unroll
    for (int j = 0; j < 4; ++j) {
        int idx = base + t * 4 + j;
        v[j] = (idx < n) ? cnt[idx] : 0;
        s += v[j];
    }
    sh[t] = s;
    __syncthreads();
    for (int off = 1; off < 256; off <<= 1) {
        int x = (t >= off) ? sh[t - off] : 0;
        __syncthreads();
        sh[t] += x;
        __syncthreads();
    }
    int run = sh[t] - s;
    if (t == 255) csums[blockIdx.x] = sh[255];
#pragma unroll
    for (int j = 0; j < 4; ++j) {
        int idx = base + t * 4 + j;
        if (idx < n) excl[idx] = run;
        run += v[j];
    }
}

__global__ void scan_sums(int* __restrict__ csums, int nChunks) {  // nChunks <= 256
    __shared__ int sh[256];
    int t = threadIdx.x;
    int v = (t < nChunks) ? csums[t] : 0;
    sh[t] = v;
    __syncthreads();
    for (int off = 1; off < 256; off <<= 1) {
        int x = (t >= off) ? sh[t - off] : 0;
        __syncthreads();
        sh[t] += x;
        __syncthreads();
    }
    if (t < nChunks) csums[t] = sh[t] - v;
}

__global__ void scan_add(int* __restrict__ row_ptr, const int* __restrict__ csums,
                         int n, int E) {
    int idx = blockIdx.x * BLK + threadIdx.x;
    if (idx < n) row_ptr[idx] += csums[idx >> 10];
    if (idx == 0) row_ptr[n] = E;
}

// ---------- bucketed CSR build ----------
__global__ void bcur_init(const int* __restrict__ row_ptr, int* __restrict__ bcur, int NB) {
    int b = blockIdx.x * BLK + threadIdx.x;
    if (b < NB) bcur[b] = row_ptr[b << SB];
}

// append (src,dst) to dst-bucket regions; 782 hot cursors -> lines fill fast
__global__ void bucket_pairs(const int* __restrict__ src, const int* __restrict__ dst,
                             int* __restrict__ bcur, int2* __restrict__ buf2, int E) {
    int e = blockIdx.x * BLK + threadIdx.x;
    if (e < E) {
        int d = dst[e];
        int p = atomicAdd(&bcur[d >> SB], 1);
        buf2[p] = make_int2(src[e], d);
    }
}

// one block per bucket: scatter srcs into the bucket's contiguous csr window
__global__ __launch_bounds__(256) void csr_from_buckets(
    const int2* __restrict__ buf2, const int* __restrict__ row_ptr,
    int* __restrict__ csr, int N) {
    __shared__ int cnt2[1 << SB];
    int b = blockIdx.x;
    int nb0 = b << SB;
    int nb1 = nb0 + (1 << SB); if (nb1 > N) nb1 = N;
    int t = threadIdx.x;
    if (t < (1 << SB)) cnt2[t] = 0;
    __syncthreads();
    int beg = row_ptr[nb0], end = row_ptr[nb1];
    for (int ii = beg + t; ii < end; ii += 256) {
        int2 pr = buf2[ii];
        int p = row_ptr[pr.y] + atomicAdd(&cnt2[pr.y - nb0], 1);
        csr[p] = pr.x;
    }
}

// ---------- GEMM: hs(bf16, stride 64) = (X @ W) * d_inv[row] ----------
template<int K, int NOUT>
__global__ __launch_bounds__(256) void gemm_scale(
    const float* __restrict__ X, const float* __restrict__ W,
    const float* __restrict__ d_inv, unsigned short* __restrict__ hs, int M)
{
    __shared__ float Wl[K * 64];
    __shared__ float Xt[16][68];

    int t = threadIdx.x;
    for (int idx = t; idx < K * 64; idx += 256) {
        int k = idx >> 6, c = idx & 63;
        Wl[idx] = (c < NOUT) ? W[k * NOUT + c] : 0.0f;
    }

    int row0 = blockIdx.x * 64;
    int tr = t >> 4, tc = t & 15;
    int lr = t >> 2, lq = t & 3;
    float a[4][4] = {};

    for (int k0 = 0; k0 < K; k0 += 16) {
        __syncthreads();
        int grow = row0 + lr;
        float4 xv = make_float4(0.f, 0.f, 0.f, 0.f);
        if (grow < M) xv = *(const float4*)(X + (size_t)grow * K + k0 + lq * 4);
        Xt[lq * 4 + 0][lr] = xv.x; Xt[lq * 4 + 1][lr] = xv.y;
        Xt[lq * 4 + 2][lr] = xv.z; Xt[lq * 4 + 3][lr] = xv.w;
        __syncthreads();

#pragma unroll 4
        for (int kk = 0; kk < 16; ++kk) {
            float4 xr = *(const float4*)(&Xt[kk][tr * 4]);
            float4 wr = *(const float4*)(&Wl[(k0 + kk) * 64 + tc * 4]);
            const float xs[4] = {xr.x, xr.y, xr.z, xr.w};
            const float wsr[4] = {wr.x, wr.y, wr.z, wr.w};
#pragma unroll
            for (int i = 0; i < 4; ++i)
#pragma unroll
                for (int j = 0; j < 4; ++j)
                    a[i][j] += xs[i] * wsr[j];
        }
    }

#pragma unroll
    for (int i = 0; i < 4; ++i) {
        int r = row0 + tr * 4 + i;
        if (r < M) {
            float s = d_inv[r];
            int c = tc * 4;
            float v0 = (c + 0 < NOUT) ? a[i][0] * s : 0.0f;
            float v1 = (c + 1 < NOUT) ? a[i][1] * s : 0.0f;
            float v2 = (c + 2 < NOUT) ? a[i][2] * s : 0.0f;
            float v3 = (c + 3 < NOUT) ? a[i][3] * s : 0.0f;
            uint2 u;
            u.x = pk(bf_rne(v0), bf_rne(v1));
            u.y = pk(bf_rne(v2), bf_rne(v3));
            *(uint2*)(hs + (size_t)r * 64 + c) = u;   // 8B store, stride 64 bf16
        }
    }
}

// ---------- fused aggregate + epilogue ----------
// One wave/node. lane = g*8+q: g = edge subgroup (8 edges in flight),
// q = dim octet (8 bf16 = 16B). Reduce groups via shfl_xor(8,16,32).
template<int DACT, bool RELU, int OSTRIDE>
__global__ __launch_bounds__(256) void agg8(
    const unsigned short* __restrict__ hs, const int* __restrict__ row_ptr,
    const int* __restrict__ csr, const float* __restrict__ dinv,
    const float* __restrict__ b, float* __restrict__ out, int N)
{
    int wave = (blockIdx.x * 256 + threadIdx.x) >> 6;
    int lane = threadIdx.x & 63;
    if (wave >= N) return;
    int i = wave;
    int g = lane >> 3, q = lane & 7;
    const uint4* hsv = (const uint4*)hs;      // row = 8 x uint4 (128B)

    int beg = row_ptr[i], end = row_ptr[i + 1];
    float acc[8] = {0.f, 0.f, 0.f, 0.f, 0.f, 0.f, 0.f, 0.f};

    for (int c = beg; c < end; c += 64) {
        int m = end - c; if (m > 64) m = 64;
        int s_l = (c + lane < end) ? csr[c + lane] : 0;  // coalesced src prefetch
        int nIter = (m + 7) >> 3;
        for (int k = 0; k < nIter; ++k) {
            int ei = k * 8 + g;
            int s = __shfl(s_l, ei, 64);
            if (ei < m) {
                uint4 u = hsv[(size_t)s * 8 + q];
                acc[0] += __uint_as_float(u.x << 16);
                acc[1] += __uint_as_float(u.x & 0xffff0000u);
                acc[2] += __uint_as_float(u.y << 16);
                acc[3] += __uint_as_float(u.y & 0xffff0000u);
                acc[4] += __uint_as_float(u.z << 16);
                acc[5] += __uint_as_float(u.z & 0xffff0000u);
                acc[6] += __uint_as_float(u.w << 16);
                acc[7] += __uint_as_float(u.w & 0xffff0000u);
            }
        }
    }

#pragma unroll
    for (int off = 8; off < 64; off <<= 1)
#pragma unroll
        for (int j = 0; j < 8; ++j)
            acc[j] += __shfl_xor(acc[j], off, 64);

    if (g == 0 && q * 8 < DACT) {
        uint4 u = hsv[(size_t)i * 8 + q];                // self-loop row
        acc[0] += __uint_as_float(u.x << 16);
        acc[1] += __uint_as_float(u.x & 0xffff0000u);
        acc[2] += __uint_as_float(u.y << 16);
        acc[3] += __uint_as_float(u.y & 0xffff0000u);
        acc[4] += __uint_as_float(u.z << 16);
        acc[5] += __uint_as_float(u.z & 0xffff0000u);
        acc[6] += __uint_as_float(u.w << 16);
        acc[7] += __uint_as_float(u.w & 0xffff0000u);
        float di = dinv[i];
        const float4 b0 = *(const float4*)(b + q * 8);
        const float4 b1 = *(const float4*)(b + q * 8 + 4);
        float4 v0, v1;
        v0.x = di * acc[0] + b0.x; v0.y = di * acc[1] + b0.y;
        v0.z = di * acc[2] + b0.z; v0.w = di * acc[3] + b0.w;
        v1.x = di * acc[4] + b1.x; v1.y = di * acc[5] + b1.y;
        v1.z = di * acc[6] + b1.z; v1.w = di * acc[7] + b1.w;
        if (RELU) {
            v0.x = fmaxf(v0.x, 0.f); v0.y = fmaxf(v0.y, 0.f);
            v0.z = fmaxf(v0.z, 0.f); v0.w = fmaxf(v0.w, 0.f);
            v1.x = fmaxf(v1.x, 0.f); v1.y = fmaxf(v1.y, 0.f);
            v1.z = fmaxf(v1.z, 0.f); v1.w = fmaxf(v1.w, 0.f);
        }
        *(float4*)(out + (size_t)i * OSTRIDE + q * 8)     = v0;
        *(float4*)(out + (size_t)i * OSTRIDE + q * 8 + 4) = v1;
    }
}

extern "C" void kernel_launch(void* const* d_in, const int* in_sizes, int n_in,
                              void* d_out, int out_size, void* d_ws, size_t ws_size,
                              hipStream_t stream) {
    const float* x   = (const float*)d_in[0];
    const int*   ei  = (const int*)  d_in[1];
    const float* W1  = (const float*)d_in[2];
    const float* bb1 = (const float*)d_in[3];
    const float* W2  = (const float*)d_in[4];
    const float* bb2 = (const float*)d_in[5];
    const float* W3  = (const float*)d_in[6];
    const float* bb3 = (const float*)d_in[7];
    float* out = (float*)d_out;

    const int N = in_sizes[0] / 128;      // 100000
    const int E = in_sizes[1] / 2;        // 1600000
    const int* src = ei;
    const int* dst = ei + E;
    const int NB = (N + (1 << SB) - 1) >> SB;   // 782 buckets

    // workspace layout (4-byte units)
    float* ws = (float*)d_ws;
    const size_t NP  = ((size_t)N + 255) & ~255ull;
    const size_t N64 = (size_t)N * 64;
    float* dinv = ws;                                   // NP
    unsigned short* bufHs = (unsigned short*)(ws + NP); // N*64 bf16 = N*32 slots
    float* bufO = ws + NP + (size_t)N * 32;             // N*64 fp32 activations
    int*   row_ptr = (int*)(bufO + N64);                // N+1
    int*   cnt     = row_ptr + (N + 1);                 // N
    int*   csums   = cnt + N;                           // 256
    int*   bcur    = csums + 256;                       // NB
    int2*  buf2    = (int2*)(bcur + ((NB + 1) & ~1));   // E pairs (8B aligned)
    int*   csr     = (int*)(buf2 + E);                  // E

    dim3 blk(BLK);
    int gN = (N + BLK - 1) / BLK;
    int gE = (E + BLK - 1) / BLK;
    int gRows = (N + 63) / 64;
    int gWave = (N * 64 + BLK - 1) / BLK;    // one wave per node
    int nChunks = (N + 1023) / 1024;

    // ---- degrees + row_ptr ----
    zero_int<<<gN, blk, 0, stream>>>(cnt, N);
    hist_dst<<<gE, blk, 0, stream>>>(dst, cnt, E);
    dinv_from_cnt<<<gN, blk, 0, stream>>>(cnt, dinv, N);
    scan_chunks<<<nChunks, blk, 0, stream>>>(cnt, row_ptr, csums, N);
    scan_sums<<<1, blk, 0, stream>>>(csums, nChunks);
    scan_add<<<gN, blk, 0, stream>>>(row_ptr, csums, N, E);

    // ---- bucketed CSR build ----
    bcur_init<<<(NB + BLK - 1) / BLK, blk, 0, stream>>>(row_ptr, bcur, NB);
    bucket_pairs<<<gE, blk, 0, stream>>>(src, dst, bcur, buf2, E);
    csr_from_buckets<<<NB, blk, 0, stream>>>(buf2, row_ptr, csr, N);

    // ---- layer 1: 128 -> 64, relu ----
    gemm_scale<128, 64><<<gRows, blk, 0, stream>>>(x, W1, dinv, bufHs, N);
    agg8<64, true, 64><<<gWave, blk, 0, stream>>>(bufHs, row_ptr, csr, dinv, bb1, bufO, N);

    // ---- layer 2: 64 -> 64, relu ----
    gemm_scale<64, 64><<<gRows, blk, 0, stream>>>(bufO, W2, dinv, bufHs, N);
    agg8<64, true, 64><<<gWave, blk, 0, stream>>>(bufHs, row_ptr, csr, dinv, bb2, bufO, N);

    // ---- layer 3: 64 -> 40 (bf16 rows zero-padded to 64), no relu ----
    gemm_scale<64, 40><<<gRows, blk, 0, stream>>>(bufO, W3, dinv, bufHs, N);
    agg8<40, false, 40><<<gWave, blk, 0, stream>>>(bufHs, row_ptr, csr, dinv, bb3, out, N);
}

// Round 5
// 419.736 us; speedup vs baseline: 1.8367x; 1.8367x over previous
//
#include <hip/hip_runtime.h>
#include <hip/hip_bf16.h>

// GCN 3-layer. CSR built by 3-pass LDS-binned partition (no hot global
// atomics, no cross-XCD line sharing). bf16 gather table:
//   hs(bf16) = (X@W) * d_inv[row]   (fp32 GEMM, bf16 RNE epilogue, stride 64)
//   out_i = act(d_inv[i]*(hs_i + sum_{e:dst=i} hs[src_e]) + b)

constexpr int BLK = 256;
constexpr int SB2 = 9;                  // partition bucket = 512 nodes
constexpr int EPB = 4096;               // edges per partition block

__device__ inline unsigned short bf_rne(float f) {
    unsigned int u = __float_as_uint(f);
    unsigned int r = (u + 0x7fffu + ((u >> 16) & 1u)) >> 16;
    return (unsigned short)r;
}
__device__ inline unsigned int pk(unsigned short lo, unsigned short hi) {
    return (unsigned int)lo | ((unsigned int)hi << 16);
}

// ---------- utility ----------
__global__ void zero_int(int* p, int n) {
    int i = blockIdx.x * BLK + threadIdx.x;
    if (i < n) p[i] = 0;
}

__global__ void hist_dst(const int* __restrict__ dst, int* __restrict__ cnt, int E) {
    int e = blockIdx.x * BLK + threadIdx.x;
    if (e < E) atomicAdd(&cnt[dst[e]], 1);
}

__global__ void dinv_from_cnt(const int* __restrict__ cnt, float* __restrict__ dinv, int n) {
    int i = blockIdx.x * BLK + threadIdx.x;
    if (i < n) dinv[i] = rsqrtf((float)cnt[i] + 1.0f);   // +1 self-loop
}

// ---------- exclusive scan for row_ptr (chunk = 1024 elements) ----------
__global__ void scan_chunks(const int* __restrict__ cnt, int* __restrict__ excl,
                            int* __restrict__ csums, int n) {
    __shared__ int sh[256];
    int t = threadIdx.x;
    int base = blockIdx.x * 1024;
    int v[4]; int s = 0;
#pragma unroll
    for (int j = 0; j < 4; ++j) {
        int idx = base + t * 4 + j;
        v[j] = (idx < n) ? cnt[idx] : 0;
        s += v[j];
    }
    sh[t] = s;
    __syncthreads();
    for (int off = 1; off < 256; off <<= 1) {
        int x = (t >= off) ? sh[t - off] : 0;
        __syncthreads();
        sh[t] += x;
        __syncthreads();
    }
    int run = sh[t] - s;
    if (t == 255) csums[blockIdx.x] = sh[255];
#pragma unroll
    for (int j = 0; j < 4; ++j) {
        int idx = base + t * 4 + j;
        if (idx < n) excl[idx] = run;
        run += v[j];
    }
}

__global__ void scan_sums(int* __restrict__ csums, int nChunks) {  // nChunks <= 256
    __shared__ int sh[256];
    int t = threadIdx.x;
    int v = (t < nChunks) ? csums[t] : 0;
    sh[t] = v;
    __syncthreads();
    for (int off = 1; off < 256; off <<= 1) {
        int x = (t >= off) ? sh[t - off] : 0;
        __syncthreads();
        sh[t] += x;
        __syncthreads();
    }
    if (t < nChunks) csums[t] = sh[t] - v;
}

__global__ void scan_add(int* __restrict__ row_ptr, const int* __restrict__ csums,
                         int n, int E) {
    int idx = blockIdx.x * BLK + threadIdx.x;
    if (idx < n) row_ptr[idx] += csums[idx >> 10];
    if (idx == 0) row_ptr[n] = E;
}

// ---------- 3-pass binned partition ----------
// Pass A: per-block histogram of dst>>SB2   (bh[b * nblk + k])
__global__ __launch_bounds__(256) void part_hist(
    const int* __restrict__ dst, int* __restrict__ bh, int E, int nblk, int NB2) {
    __shared__ int lh[256];               // NB2 <= 256
    int k = blockIdx.x, t = threadIdx.x;
    lh[t] = 0;
    __syncthreads();
    int e0 = k * EPB;
#pragma unroll
    for (int j = 0; j < EPB / 256; ++j) {
        int e = e0 + j * 256 + t;
        if (e < E) atomicAdd(&lh[dst[e] >> SB2], 1);
    }
    __syncthreads();
    if (t < NB2) bh[t * nblk + k] = lh[t];
}

// Pass A': per bucket, exclusive scan over blocks (+ bucket base from row_ptr)
__global__ __launch_bounds__(256) void part_scan(
    int* __restrict__ bh, const int* __restrict__ row_ptr, int nblk, int N) {
    __shared__ int sh[256];
    int b = blockIdx.x, t = threadIdx.x;
    int base = row_ptr[b << SB2];         // bucket's first edge (nb0 < N always)
    int v[4]; int s = 0;                  // supports nblk <= 1024
#pragma unroll
    for (int j = 0; j < 4; ++j) {
        int idx = t * 4 + j;
        v[j] = (idx < nblk) ? bh[b * nblk + idx] : 0;
        s += v[j];
    }
    sh[t] = s;
    __syncthreads();
    for (int off = 1; off < 256; off <<= 1) {
        int x = (t >= off) ? sh[t - off] : 0;
        __syncthreads();
        sh[t] += x;
        __syncthreads();
    }
    int run = sh[t] - s;
#pragma unroll
    for (int j = 0; j < 4; ++j) {
        int idx = t * 4 + j;
        if (idx < nblk) bh[b * nblk + idx] = base + run;
        run += v[j];
    }
}

// Pass B: scatter (src,dst) pairs into private (block,bucket) runs
__global__ __launch_bounds__(256) void part_scatter(
    const int* __restrict__ src, const int* __restrict__ dst,
    const int* __restrict__ bh, int2* __restrict__ buf2, int E, int nblk, int NB2) {
    __shared__ int lbase[256];
    __shared__ int lcnt[256];
    int k = blockIdx.x, t = threadIdx.x;
    lcnt[t] = 0;
    if (t < NB2) lbase[t] = bh[t * nblk + k];
    __syncthreads();
    int e0 = k * EPB;
#pragma unroll
    for (int j = 0; j < EPB / 256; ++j) {
        int e = e0 + j * 256 + t;
        if (e < E) {
            int d = dst[e];
            int b = d >> SB2;
            int p = lbase[b] + atomicAdd(&lcnt[b], 1);
            buf2[p] = make_int2(src[e], d);
        }
    }
}

// Pass C: block per bucket -> final CSR within cache-resident window
__global__ __launch_bounds__(256) void csr_from_parts(
    const int2* __restrict__ buf2, const int* __restrict__ row_ptr,
    int* __restrict__ csr, int N) {
    __shared__ int cnt3[1 << SB2];        // 512
    int b = blockIdx.x, t = threadIdx.x;
    int nb0 = b << SB2;
    int nb1 = nb0 + (1 << SB2); if (nb1 > N) nb1 = N;
    for (int j = t; j < (1 << SB2); j += 256) cnt3[j] = 0;
    __syncthreads();
    int beg = row_ptr[nb0], end = row_ptr[nb1];
    for (int i = beg + t; i < end; i += 256) {
        int2 pr = buf2[i];
        int p = row_ptr[pr.y] + atomicAdd(&cnt3[pr.y - nb0], 1);
        csr[p] = pr.x;
    }
}

// ---------- GEMM: hs(bf16, stride 64) = (X @ W) * d_inv[row] ----------
template<int K, int NOUT>
__global__ __launch_bounds__(256) void gemm_scale(
    const float* __restrict__ X, const float* __restrict__ W,
    const float* __restrict__ d_inv, unsigned short* __restrict__ hs, int M)
{
    __shared__ float Wl[K * 64];
    __shared__ float Xt[16][68];

    int t = threadIdx.x;
    for (int idx = t; idx < K * 64; idx += 256) {
        int k = idx >> 6, c = idx & 63;
        Wl[idx] = (c < NOUT) ? W[k * NOUT + c] : 0.0f;
    }

    int row0 = blockIdx.x * 64;
    int tr = t >> 4, tc = t & 15;
    int lr = t >> 2, lq = t & 3;
    float a[4][4] = {};

    for (int k0 = 0; k0 < K; k0 += 16) {
        __syncthreads();
        int grow = row0 + lr;
        float4 xv = make_float4(0.f, 0.f, 0.f, 0.f);
        if (grow < M) xv = *(const float4*)(X + (size_t)grow * K + k0 + lq * 4);
        Xt[lq * 4 + 0][lr] = xv.x; Xt[lq * 4 + 1][lr] = xv.y;
        Xt[lq * 4 + 2][lr] = xv.z; Xt[lq * 4 + 3][lr] = xv.w;
        __syncthreads();

#pragma unroll 4
        for (int kk = 0; kk < 16; ++kk) {
            float4 xr = *(const float4*)(&Xt[kk][tr * 4]);
            float4 wr = *(const float4*)(&Wl[(k0 + kk) * 64 + tc * 4]);
            const float xs[4] = {xr.x, xr.y, xr.z, xr.w};
            const float wsr[4] = {wr.x, wr.y, wr.z, wr.w};
#pragma unroll
            for (int i = 0; i < 4; ++i)
#pragma unroll
                for (int j = 0; j < 4; ++j)
                    a[i][j] += xs[i] * wsr[j];
        }
    }

#pragma unroll
    for (int i = 0; i < 4; ++i) {
        int r = row0 + tr * 4 + i;
        if (r < M) {
            float s = d_inv[r];
            int c = tc * 4;
            float v0 = (c + 0 < NOUT) ? a[i][0] * s : 0.0f;
            float v1 = (c + 1 < NOUT) ? a[i][1] * s : 0.0f;
            float v2 = (c + 2 < NOUT) ? a[i][2] * s : 0.0f;
            float v3 = (c + 3 < NOUT) ? a[i][3] * s : 0.0f;
            uint2 u;
            u.x = pk(bf_rne(v0), bf_rne(v1));
            u.y = pk(bf_rne(v2), bf_rne(v3));
            *(uint2*)(hs + (size_t)r * 64 + c) = u;
        }
    }
}

// ---------- fused aggregate + epilogue ----------
template<int DACT, bool RELU, int OSTRIDE>
__global__ __launch_bounds__(256) void agg8(
    const unsigned short* __restrict__ hs, const int* __restrict__ row_ptr,
    const int* __restrict__ csr, const float* __restrict__ dinv,
    const float* __restrict__ b, float* __restrict__ out, int N)
{
    int wave = (blockIdx.x * 256 + threadIdx.x) >> 6;
    int lane = threadIdx.x & 63;
    if (wave >= N) return;
    int i = wave;
    int g = lane >> 3, q = lane & 7;
    const uint4* hsv = (const uint4*)hs;      // row = 8 x uint4 (128B)

    int beg = row_ptr[i], end = row_ptr[i + 1];
    float acc[8] = {0.f, 0.f, 0.f, 0.f, 0.f, 0.f, 0.f, 0.f};

    for (int c = beg; c < end; c += 64) {
        int m = end - c; if (m > 64) m = 64;
        int s_l = (c + lane < end) ? csr[c + lane] : 0;
        int nIter = (m + 7) >> 3;
        for (int k = 0; k < nIter; ++k) {
            int ei = k * 8 + g;
            int s = __shfl(s_l, ei, 64);
            if (ei < m) {
                uint4 u = hsv[(size_t)s * 8 + q];
                acc[0] += __uint_as_float(u.x << 16);
                acc[1] += __uint_as_float(u.x & 0xffff0000u);
                acc[2] += __uint_as_float(u.y << 16);
                acc[3] += __uint_as_float(u.y & 0xffff0000u);
                acc[4] += __uint_as_float(u.z << 16);
                acc[5] += __uint_as_float(u.z & 0xffff0000u);
                acc[6] += __uint_as_float(u.w << 16);
                acc[7] += __uint_as_float(u.w & 0xffff0000u);
            }
        }
    }

#pragma unroll
    for (int off = 8; off < 64; off <<= 1)
#pragma unroll
        for (int j = 0; j < 8; ++j)
            acc[j] += __shfl_xor(acc[j], off, 64);

    if (g == 0 && q * 8 < DACT) {
        uint4 u = hsv[(size_t)i * 8 + q];                // self-loop row
        acc[0] += __uint_as_float(u.x << 16);
        acc[1] += __uint_as_float(u.x & 0xffff0000u);
        acc[2] += __uint_as_float(u.y << 16);
        acc[3] += __uint_as_float(u.y & 0xffff0000u);
        acc[4] += __uint_as_float(u.z << 16);
        acc[5] += __uint_as_float(u.z & 0xffff0000u);
        acc[6] += __uint_as_float(u.w << 16);
        acc[7] += __uint_as_float(u.w & 0xffff0000u);
        float di = dinv[i];
        const float4 b0 = *(const float4*)(b + q * 8);
        const float4 b1 = *(const float4*)(b + q * 8 + 4);
        float4 v0, v1;
        v0.x = di * acc[0] + b0.x; v0.y = di * acc[1] + b0.y;
        v0.z = di * acc[2] + b0.z; v0.w = di * acc[3] + b0.w;
        v1.x = di * acc[4] + b1.x; v1.y = di * acc[5] + b1.y;
        v1.z = di * acc[6] + b1.z; v1.w = di * acc[7] + b1.w;
        if (RELU) {
            v0.x = fmaxf(v0.x, 0.f); v0.y = fmaxf(v0.y, 0.f);
            v0.z = fmaxf(v0.z, 0.f); v0.w = fmaxf(v0.w, 0.f);
            v1.x = fmaxf(v1.x, 0.f); v1.y = fmaxf(v1.y, 0.f);
            v1.z = fmaxf(v1.z, 0.f); v1.w = fmaxf(v1.w, 0.f);
        }
        *(float4*)(out + (size_t)i * OSTRIDE + q * 8)     = v0;
        *(float4*)(out + (size_t)i * OSTRIDE + q * 8 + 4) = v1;
    }
}

extern "C" void kernel_launch(void* const* d_in, const int* in_sizes, int n_in,
                              void* d_out, int out_size, void* d_ws, size_t ws_size,
                              hipStream_t stream) {
    const float* x   = (const float*)d_in[0];
    const int*   ei  = (const int*)  d_in[1];
    const float* W1  = (const float*)d_in[2];
    const float* bb1 = (const float*)d_in[3];
    const float* W2  = (const float*)d_in[4];
    const float* bb2 = (const float*)d_in[5];
    const float* W3  = (const float*)d_in[6];
    const float* bb3 = (const float*)d_in[7];
    float* out = (float*)d_out;

    const int N = in_sizes[0] / 128;      // 100000
    const int E = in_sizes[1] / 2;        // 1600000
    const int* src = ei;
    const int* dst = ei + E;
    const int NB2  = (N + (1 << SB2) - 1) >> SB2;   // 196 buckets (<=256)
    const int nblk = (E + EPB - 1) / EPB;           // 391 partition blocks (<=1024)

    // workspace layout (4-byte units)
    float* ws = (float*)d_ws;
    const size_t NP  = ((size_t)N + 255) & ~255ull;
    const size_t N64 = (size_t)N * 64;
    float* dinv = ws;                                   // NP
    unsigned short* bufHs = (unsigned short*)(ws + NP); // N*64 bf16 = N*32 slots
    float* bufO = ws + NP + (size_t)N * 32;             // N*64 fp32 activations
    int*   row_ptr = (int*)(bufO + N64);                // N+1 (pad to N+2)
    int*   cnt     = row_ptr + (((size_t)N + 2) & ~1ull);  // N
    int*   csums   = cnt + N;                           // 256
    int*   bh      = csums + 256;                       // NB2*nblk (pad even)
    size_t bhsz    = ((size_t)NB2 * nblk + 1) & ~1ull;
    int2*  buf2    = (int2*)(bh + bhsz);                // E pairs (8B aligned)
    int*   csr     = (int*)(buf2 + E);                  // E

    dim3 blk(BLK);
    int gN = (N + BLK - 1) / BLK;
    int gE = (E + BLK - 1) / BLK;
    int gRows = (N + 63) / 64;
    int gWave = (N * 64 + BLK - 1) / BLK;    // one wave per node
    int nChunks = (N + 1023) / 1024;

    // ---- degrees + row_ptr ----
    zero_int<<<gN, blk, 0, stream>>>(cnt, N);
    hist_dst<<<gE, blk, 0, stream>>>(dst, cnt, E);
    dinv_from_cnt<<<gN, blk, 0, stream>>>(cnt, dinv, N);
    scan_chunks<<<nChunks, blk, 0, stream>>>(cnt, row_ptr, csums, N);
    scan_sums<<<1, blk, 0, stream>>>(csums, nChunks);
    scan_add<<<gN, blk, 0, stream>>>(row_ptr, csums, N, E);

    // ---- binned partition -> CSR ----
    part_hist<<<nblk, blk, 0, stream>>>(dst, bh, E, nblk, NB2);
    part_scan<<<NB2, blk, 0, stream>>>(bh, row_ptr, nblk, N);
    part_scatter<<<nblk, blk, 0, stream>>>(src, dst, bh, buf2, E, nblk, NB2);
    csr_from_parts<<<NB2, blk, 0, stream>>>(buf2, row_ptr, csr, N);

    // ---- layer 1: 128 -> 64, relu ----
    gemm_scale<128, 64><<<gRows, blk, 0, stream>>>(x, W1, dinv, bufHs, N);
    agg8<64, true, 64><<<gWave, blk, 0, stream>>>(bufHs, row_ptr, csr, dinv, bb1, bufO, N);

    // ---- layer 2: 64 -> 64, relu ----
    gemm_scale<64, 64><<<gRows, blk, 0, stream>>>(bufO, W2, dinv, bufHs, N);
    agg8<64, true, 64><<<gWave, blk, 0, stream>>>(bufHs, row_ptr, csr, dinv, bb2, bufO, N);

    // ---- layer 3: 64 -> 40 (bf16 rows zero-padded to 64), no relu ----
    gemm_scale<64, 40><<<gRows, blk, 0, stream>>>(bufO, W3, dinv, bufHs, N);
    agg8<40, false, 40><<<gWave, blk, 0, stream>>>(bufHs, row_ptr, csr, dinv, bb3, out, N);
}

// Round 6
// 353.395 us; speedup vs baseline: 2.1815x; 1.1877x over previous
//
#include <hip/hip_runtime.h>
#include <hip/hip_bf16.h>

// GCN 3-layer. CSR built by LDS-binned partition; ALL node-level counting
// done per-bucket in LDS (no global atomic histogram anywhere).
//   hs(bf16) = (X@W) * d_inv[row]   (fp32 GEMM, bf16 RNE epilogue, stride 64)
//   out_i = act(d_inv[i]*(hs_i + sum_{e:dst=i} hs[src_e]) + b)

constexpr int BLK = 256;
constexpr int SB2 = 9;                  // bucket = 512 nodes
constexpr int EPB = 4096;               // edges per partition block
// packed partition word: (local_node_id << 23) | src   (requires N < 2^23)

__device__ inline unsigned short bf_rne(float f) {
    unsigned int u = __float_as_uint(f);
    unsigned int r = (u + 0x7fffu + ((u >> 16) & 1u)) >> 16;
    return (unsigned short)r;
}
__device__ inline unsigned int pk(unsigned short lo, unsigned short hi) {
    return (unsigned int)lo | ((unsigned int)hi << 16);
}

// ---------- Pass A: per-block histogram of dst>>SB2 ----------
__global__ __launch_bounds__(256) void part_hist(
    const int* __restrict__ dst, int* __restrict__ bh, int E, int nblk, int NB2) {
    __shared__ int lh[256];               // NB2 <= 256
    int k = blockIdx.x, t = threadIdx.x;
    lh[t] = 0;
    __syncthreads();
    int e0 = k * EPB;
#pragma unroll
    for (int j = 0; j < EPB / 256; ++j) {
        int e = e0 + j * 256 + t;
        if (e < E) atomicAdd(&lh[dst[e] >> SB2], 1);
    }
    __syncthreads();
    if (t < NB2) bh[t * nblk + k] = lh[t];
}

// ---------- bucket totals: btot[b] = sum_k bh[b][k] ----------
__global__ __launch_bounds__(256) void bucket_totals(
    const int* __restrict__ bh, int* __restrict__ btot, int nblk) {
    __shared__ int sh[256];
    int b = blockIdx.x, t = threadIdx.x;
    int s = 0;
    for (int i = t; i < nblk; i += 256) s += bh[b * nblk + i];
    sh[t] = s;
    __syncthreads();
    for (int off = 128; off > 0; off >>= 1) {
        if (t < off) sh[t] += sh[t + off];
        __syncthreads();
    }
    if (t == 0) btot[b] = sh[0];
}

// ---------- bucket base: exclusive scan of btot (NB2 <= 256) ----------
__global__ void bucket_scan(const int* __restrict__ btot, int* __restrict__ bbase, int NB2) {
    __shared__ int sh[256];
    int t = threadIdx.x;
    int v = (t < NB2) ? btot[t] : 0;
    sh[t] = v;
    __syncthreads();
    for (int off = 1; off < 256; off <<= 1) {
        int x = (t >= off) ? sh[t - off] : 0;
        __syncthreads();
        sh[t] += x;
        __syncthreads();
    }
    if (t < NB2) bbase[t] = sh[t] - v;
}

// ---------- Pass A': per bucket, exclusive scan over blocks + bucket base ----------
__global__ __launch_bounds__(256) void part_scan(
    int* __restrict__ bh, const int* __restrict__ bbase, int nblk) {
    __shared__ int sh[256];
    int b = blockIdx.x, t = threadIdx.x;
    int base = bbase[b];
    int v[4]; int s = 0;                  // supports nblk <= 1024
#pragma unroll
    for (int j = 0; j < 4; ++j) {
        int idx = t * 4 + j;
        v[j] = (idx < nblk) ? bh[b * nblk + idx] : 0;
        s += v[j];
    }
    sh[t] = s;
    __syncthreads();
    for (int off = 1; off < 256; off <<= 1) {
        int x = (t >= off) ? sh[t - off] : 0;
        __syncthreads();
        sh[t] += x;
        __syncthreads();
    }
    int run = sh[t] - s;
#pragma unroll
    for (int j = 0; j < 4; ++j) {
        int idx = t * 4 + j;
        if (idx < nblk) bh[b * nblk + idx] = base + run;
        run += v[j];
    }
}

// ---------- Pass B: scatter packed (local,src) into private (block,bucket) runs ----------
__global__ __launch_bounds__(256) void part_scatter(
    const int* __restrict__ src, const int* __restrict__ dst,
    const int* __restrict__ bh, unsigned int* __restrict__ buf,
    int E, int nblk, int NB2) {
    __shared__ int lbase[256];
    __shared__ int lcnt[256];
    int k = blockIdx.x, t = threadIdx.x;
    lcnt[t] = 0;
    if (t < NB2) lbase[t] = bh[t * nblk + k];
    __syncthreads();
    int e0 = k * EPB;
#pragma unroll
    for (int j = 0; j < EPB / 256; ++j) {
        int e = e0 + j * 256 + t;
        if (e < E) {
            int d = dst[e];
            int b = d >> SB2;
            int p = lbase[b] + atomicAdd(&lcnt[b], 1);
            buf[p] = ((unsigned int)(d & ((1 << SB2) - 1)) << 23) | (unsigned int)src[e];
        }
    }
}

// ---------- Pass C: per bucket — node hist, scan, row_ptr+dinv, csr scatter ----------
__global__ __launch_bounds__(256) void csr_finalize(
    const unsigned int* __restrict__ buf, const int* __restrict__ bbase,
    int* __restrict__ row_ptr, float* __restrict__ dinv,
    int* __restrict__ csr, int N, int E, int NB2) {
    __shared__ int hist[1 << SB2];        // 512
    __shared__ int excl[1 << SB2];
    __shared__ int ssc[256];
    int b = blockIdx.x, t = threadIdx.x;
    int nb0 = b << SB2;
    int nn = N - nb0; if (nn > (1 << SB2)) nn = 1 << SB2;
    int beg = bbase[b];
    int end = (b + 1 < NB2) ? bbase[b + 1] : E;

    hist[t] = 0; hist[t + 256] = 0;
    __syncthreads();
    for (int i = beg + t; i < end; i += 256)
        atomicAdd(&hist[buf[i] >> 23], 1);
    __syncthreads();

    // exclusive scan of hist[512]: thread owns elements 2t, 2t+1
    int a0 = hist[2 * t], a1 = hist[2 * t + 1];
    int s = a0 + a1;
    ssc[t] = s;
    __syncthreads();
    for (int off = 1; off < 256; off <<= 1) {
        int x = (t >= off) ? ssc[t - off] : 0;
        __syncthreads();
        ssc[t] += x;
        __syncthreads();
    }
    int run = ssc[t] - s;
    excl[2 * t] = run;
    excl[2 * t + 1] = run + a0;
    __syncthreads();

    // emit row_ptr and dinv for this bucket's nodes
    for (int j = t; j < nn; j += 256) {
        row_ptr[nb0 + j] = beg + excl[j];
        dinv[nb0 + j] = rsqrtf((float)hist[j] + 1.0f);   // +1 self-loop
    }
    if (b == NB2 - 1 && t == 0) row_ptr[N] = E;
    __syncthreads();

    // reuse hist as write cursors
    hist[t] = 0; hist[t + 256] = 0;
    __syncthreads();
    for (int i = beg + t; i < end; i += 256) {
        unsigned int w = buf[i];
        int local = w >> 23;
        int p = beg + excl[local] + atomicAdd(&hist[local], 1);
        csr[p] = (int)(w & 0x7fffffu);
    }
}

// ---------- GEMM: hs(bf16, stride 64) = (X @ W) * d_inv[row] ----------
template<int K, int NOUT>
__global__ __launch_bounds__(256) void gemm_scale(
    const float* __restrict__ X, const float* __restrict__ W,
    const float* __restrict__ d_inv, unsigned short* __restrict__ hs, int M)
{
    __shared__ float Wl[K * 64];
    __shared__ float Xt[16][68];

    int t = threadIdx.x;
    for (int idx = t; idx < K * 64; idx += 256) {
        int k = idx >> 6, c = idx & 63;
        Wl[idx] = (c < NOUT) ? W[k * NOUT + c] : 0.0f;
    }

    int row0 = blockIdx.x * 64;
    int tr = t >> 4, tc = t & 15;
    int lr = t >> 2, lq = t & 3;
    float a[4][4] = {};

    for (int k0 = 0; k0 < K; k0 += 16) {
        __syncthreads();
        int grow = row0 + lr;
        float4 xv = make_float4(0.f, 0.f, 0.f, 0.f);
        if (grow < M) xv = *(const float4*)(X + (size_t)grow * K + k0 + lq * 4);
        Xt[lq * 4 + 0][lr] = xv.x; Xt[lq * 4 + 1][lr] = xv.y;
        Xt[lq * 4 + 2][lr] = xv.z; Xt[lq * 4 + 3][lr] = xv.w;
        __syncthreads();

#pragma unroll 4
        for (int kk = 0; kk < 16; ++kk) {
            float4 xr = *(const float4*)(&Xt[kk][tr * 4]);
            float4 wr = *(const float4*)(&Wl[(k0 + kk) * 64 + tc * 4]);
            const float xs[4] = {xr.x, xr.y, xr.z, xr.w};
            const float wsr[4] = {wr.x, wr.y, wr.z, wr.w};
#pragma unroll
            for (int i = 0; i < 4; ++i)
#pragma unroll
                for (int j = 0; j < 4; ++j)
                    a[i][j] += xs[i] * wsr[j];
        }
    }

#pragma unroll
    for (int i = 0; i < 4; ++i) {
        int r = row0 + tr * 4 + i;
        if (r < M) {
            float s = d_inv[r];
            int c = tc * 4;
            float v0 = (c + 0 < NOUT) ? a[i][0] * s : 0.0f;
            float v1 = (c + 1 < NOUT) ? a[i][1] * s : 0.0f;
            float v2 = (c + 2 < NOUT) ? a[i][2] * s : 0.0f;
            float v3 = (c + 3 < NOUT) ? a[i][3] * s : 0.0f;
            uint2 u;
            u.x = pk(bf_rne(v0), bf_rne(v1));
            u.y = pk(bf_rne(v2), bf_rne(v3));
            *(uint2*)(hs + (size_t)r * 64 + c) = u;
        }
    }
}

// ---------- fused aggregate + epilogue ----------
template<int DACT, bool RELU, int OSTRIDE>
__global__ __launch_bounds__(256) void agg8(
    const unsigned short* __restrict__ hs, const int* __restrict__ row_ptr,
    const int* __restrict__ csr, const float* __restrict__ dinv,
    const float* __restrict__ b, float* __restrict__ out, int N)
{
    int wave = (blockIdx.x * 256 + threadIdx.x) >> 6;
    int lane = threadIdx.x & 63;
    if (wave >= N) return;
    int i = wave;
    int g = lane >> 3, q = lane & 7;
    const uint4* hsv = (const uint4*)hs;      // row = 8 x uint4 (128B)

    int beg = row_ptr[i], end = row_ptr[i + 1];
    float acc[8] = {0.f, 0.f, 0.f, 0.f, 0.f, 0.f, 0.f, 0.f};

    for (int c = beg; c < end; c += 64) {
        int m = end - c; if (m > 64) m = 64;
        int s_l = (c + lane < end) ? csr[c + lane] : 0;
        int nIter = (m + 7) >> 3;
        for (int k = 0; k < nIter; ++k) {
            int ei = k * 8 + g;
            int s = __shfl(s_l, ei, 64);
            if (ei < m) {
                uint4 u = hsv[(size_t)s * 8 + q];
                acc[0] += __uint_as_float(u.x << 16);
                acc[1] += __uint_as_float(u.x & 0xffff0000u);
                acc[2] += __uint_as_float(u.y << 16);
                acc[3] += __uint_as_float(u.y & 0xffff0000u);
                acc[4] += __uint_as_float(u.z << 16);
                acc[5] += __uint_as_float(u.z & 0xffff0000u);
                acc[6] += __uint_as_float(u.w << 16);
                acc[7] += __uint_as_float(u.w & 0xffff0000u);
            }
        }
    }

#pragma unroll
    for (int off = 8; off < 64; off <<= 1)
#pragma unroll
        for (int j = 0; j < 8; ++j)
            acc[j] += __shfl_xor(acc[j], off, 64);

    if (g == 0 && q * 8 < DACT) {
        uint4 u = hsv[(size_t)i * 8 + q];                // self-loop row
        acc[0] += __uint_as_float(u.x << 16);
        acc[1] += __uint_as_float(u.x & 0xffff0000u);
        acc[2] += __uint_as_float(u.y << 16);
        acc[3] += __uint_as_float(u.y & 0xffff0000u);
        acc[4] += __uint_as_float(u.z << 16);
        acc[5] += __uint_as_float(u.z & 0xffff0000u);
        acc[6] += __uint_as_float(u.w << 16);
        acc[7] += __uint_as_float(u.w & 0xffff0000u);
        float di = dinv[i];
        const float4 b0 = *(const float4*)(b + q * 8);
        const float4 b1 = *(const float4*)(b + q * 8 + 4);
        float4 v0, v1;
        v0.x = di * acc[0] + b0.x; v0.y = di * acc[1] + b0.y;
        v0.z = di * acc[2] + b0.z; v0.w = di * acc[3] + b0.w;
        v1.x = di * acc[4] + b1.x; v1.y = di * acc[5] + b1.y;
        v1.z = di * acc[6] + b1.z; v1.w = di * acc[7] + b1.w;
        if (RELU) {
            v0.x = fmaxf(v0.x, 0.f); v0.y = fmaxf(v0.y, 0.f);
            v0.z = fmaxf(v0.z, 0.f); v0.w = fmaxf(v0.w, 0.f);
            v1.x = fmaxf(v1.x, 0.f); v1.y = fmaxf(v1.y, 0.f);
            v1.z = fmaxf(v1.z, 0.f); v1.w = fmaxf(v1.w, 0.f);
        }
        *(float4*)(out + (size_t)i * OSTRIDE + q * 8)     = v0;
        *(float4*)(out + (size_t)i * OSTRIDE + q * 8 + 4) = v1;
    }
}

extern "C" void kernel_launch(void* const* d_in, const int* in_sizes, int n_in,
                              void* d_out, int out_size, void* d_ws, size_t ws_size,
                              hipStream_t stream) {
    const float* x   = (const float*)d_in[0];
    const int*   ei  = (const int*)  d_in[1];
    const float* W1  = (const float*)d_in[2];
    const float* bb1 = (const float*)d_in[3];
    const float* W2  = (const float*)d_in[4];
    const float* bb2 = (const float*)d_in[5];
    const float* W3  = (const float*)d_in[6];
    const float* bb3 = (const float*)d_in[7];
    float* out = (float*)d_out;

    const int N = in_sizes[0] / 128;      // 100000
    const int E = in_sizes[1] / 2;        // 1600000
    const int* src = ei;
    const int* dst = ei + E;
    const int NB2  = (N + (1 << SB2) - 1) >> SB2;   // 196 buckets (<=256)
    const int nblk = (E + EPB - 1) / EPB;           // 391 partition blocks (<=1024)

    // workspace layout (4-byte units)
    float* ws = (float*)d_ws;
    const size_t NP  = ((size_t)N + 255) & ~255ull;
    const size_t N64 = (size_t)N * 64;
    float* dinv = ws;                                   // NP
    unsigned short* bufHs = (unsigned short*)(ws + NP); // N*64 bf16 = N*32 slots
    float* bufO = ws + NP + (size_t)N * 32;             // N*64 fp32 activations
    int*   row_ptr = (int*)(bufO + N64);                // N+1 (pad to N+2)
    int*   btot    = row_ptr + (((size_t)N + 2) & ~1ull);  // 256
    int*   bbase   = btot + 256;                        // 256
    int*   bh      = bbase + 256;                       // NB2*nblk (pad even)
    size_t bhsz    = ((size_t)NB2 * nblk + 1) & ~1ull;
    unsigned int* buf = (unsigned int*)(bh + bhsz);     // E packed words
    int*   csr     = (int*)(buf + E);                   // E

    dim3 blk(BLK);
    int gRows = (N + 63) / 64;
    int gWave = (N * 64 + BLK - 1) / BLK;    // one wave per node

    // ---- binned partition -> CSR + degrees (no global histogram) ----
    part_hist<<<nblk, blk, 0, stream>>>(dst, bh, E, nblk, NB2);
    bucket_totals<<<NB2, blk, 0, stream>>>(bh, btot, nblk);
    bucket_scan<<<1, blk, 0, stream>>>(btot, bbase, NB2);
    part_scan<<<NB2, blk, 0, stream>>>(bh, bbase, nblk);
    part_scatter<<<nblk, blk, 0, stream>>>(src, dst, bh, buf, E, nblk, NB2);
    csr_finalize<<<NB2, blk, 0, stream>>>(buf, bbase, row_ptr, dinv, csr, N, E, NB2);

    // ---- layer 1: 128 -> 64, relu ----
    gemm_scale<128, 64><<<gRows, blk, 0, stream>>>(x, W1, dinv, bufHs, N);
    agg8<64, true, 64><<<gWave, blk, 0, stream>>>(bufHs, row_ptr, csr, dinv, bb1, bufO, N);

    // ---- layer 2: 64 -> 64, relu ----
    gemm_scale<64, 64><<<gRows, blk, 0, stream>>>(bufO, W2, dinv, bufHs, N);
    agg8<64, true, 64><<<gWave, blk, 0, stream>>>(bufHs, row_ptr, csr, dinv, bb2, bufO, N);

    // ---- layer 3: 64 -> 40 (bf16 rows zero-padded to 64), no relu ----
    gemm_scale<64, 40><<<gRows, blk, 0, stream>>>(bufO, W3, dinv, bufHs, N);
    agg8<40, false, 40><<<gWave, blk, 0, stream>>>(bufHs, row_ptr, csr, dinv, bb3, out, N);
}

// Round 7
// 325.854 us; speedup vs baseline: 2.3659x; 1.0845x over previous
//
#include <hip/hip_runtime.h>
#include <hip/hip_bf16.h>

// GCN 3-layer. CSR via LDS-binned partition. bf16 everywhere after layer-0:
//   hs(bf16) = (A@W) * d_inv[row]   (bf16 MFMA GEMM, LDS-transposed W, fused scale)
//   act(bf16) / out(fp32) = act(d_inv[i]*(hs_i + sum_{e:dst=i} hs[src_e]) + b)

constexpr int BLK = 256;
constexpr int SB2 = 9;                  // bucket = 512 nodes
constexpr int EPB = 4096;               // edges per partition block
// packed partition word: (local_node_id << 23) | src   (requires N < 2^23)

typedef __attribute__((ext_vector_type(8))) short bf16x8;   // 8 bf16 = 4 VGPR
typedef __attribute__((ext_vector_type(4))) float f32x4;    // MFMA acc

__device__ inline unsigned short bf_rne(float f) {
    unsigned int u = __float_as_uint(f);
    unsigned int r = (u + 0x7fffu + ((u >> 16) & 1u)) >> 16;
    return (unsigned short)r;
}
__device__ inline unsigned int pk(unsigned short lo, unsigned short hi) {
    return (unsigned int)lo | ((unsigned int)hi << 16);
}

// ---------- Pass A: per-block histogram of dst>>SB2 ----------
__global__ __launch_bounds__(256) void part_hist(
    const int* __restrict__ dst, int* __restrict__ bh, int E, int nblk, int NB2) {
    __shared__ int lh[256];               // NB2 <= 256
    int k = blockIdx.x, t = threadIdx.x;
    lh[t] = 0;
    __syncthreads();
    int e0 = k * EPB;
#pragma unroll
    for (int j = 0; j < EPB / 256; ++j) {
        int e = e0 + j * 256 + t;
        if (e < E) atomicAdd(&lh[dst[e] >> SB2], 1);
    }
    __syncthreads();
    if (t < NB2) bh[t * nblk + k] = lh[t];
}

// ---------- bucket totals: btot[b] = sum_k bh[b][k] ----------
__global__ __launch_bounds__(256) void bucket_totals(
    const int* __restrict__ bh, int* __restrict__ btot, int nblk) {
    __shared__ int sh[256];
    int b = blockIdx.x, t = threadIdx.x;
    int s = 0;
    for (int i = t; i < nblk; i += 256) s += bh[b * nblk + i];
    sh[t] = s;
    __syncthreads();
    for (int off = 128; off > 0; off >>= 1) {
        if (t < off) sh[t] += sh[t + off];
        __syncthreads();
    }
    if (t == 0) btot[b] = sh[0];
}

// ---------- bucket base: exclusive scan of btot (NB2 <= 256) ----------
__global__ void bucket_scan(const int* __restrict__ btot, int* __restrict__ bbase, int NB2) {
    __shared__ int sh[256];
    int t = threadIdx.x;
    int v = (t < NB2) ? btot[t] : 0;
    sh[t] = v;
    __syncthreads();
    for (int off = 1; off < 256; off <<= 1) {
        int x = (t >= off) ? sh[t - off] : 0;
        __syncthreads();
        sh[t] += x;
        __syncthreads();
    }
    if (t < NB2) bbase[t] = sh[t] - v;
}

// ---------- Pass A': per bucket, exclusive scan over blocks + bucket base ----------
__global__ __launch_bounds__(256) void part_scan(
    int* __restrict__ bh, const int* __restrict__ bbase, int nblk) {
    __shared__ int sh[256];
    int b = blockIdx.x, t = threadIdx.x;
    int base = bbase[b];
    int v[4]; int s = 0;                  // supports nblk <= 1024
#pragma unroll
    for (int j = 0; j < 4; ++j) {
        int idx = t * 4 + j;
        v[j] = (idx < nblk) ? bh[b * nblk + idx] : 0;
        s += v[j];
    }
    sh[t] = s;
    __syncthreads();
    for (int off = 1; off < 256; off <<= 1) {
        int x = (t >= off) ? sh[t - off] : 0;
        __syncthreads();
        sh[t] += x;
        __syncthreads();
    }
    int run = sh[t] - s;
#pragma unroll
    for (int j = 0; j < 4; ++j) {
        int idx = t * 4 + j;
        if (idx < nblk) bh[b * nblk + idx] = base + run;
        run += v[j];
    }
}

// ---------- Pass B: scatter packed (local,src) into private (block,bucket) runs ----------
__global__ __launch_bounds__(256) void part_scatter(
    const int* __restrict__ src, const int* __restrict__ dst,
    const int* __restrict__ bh, unsigned int* __restrict__ buf,
    int E, int nblk, int NB2) {
    __shared__ int lbase[256];
    __shared__ int lcnt[256];
    int k = blockIdx.x, t = threadIdx.x;
    lcnt[t] = 0;
    if (t < NB2) lbase[t] = bh[t * nblk + k];
    __syncthreads();
    int e0 = k * EPB;
#pragma unroll
    for (int j = 0; j < EPB / 256; ++j) {
        int e = e0 + j * 256 + t;
        if (e < E) {
            int d = dst[e];
            int b = d >> SB2;
            int p = lbase[b] + atomicAdd(&lcnt[b], 1);
            buf[p] = ((unsigned int)(d & ((1 << SB2) - 1)) << 23) | (unsigned int)src[e];
        }
    }
}

// ---------- Pass C: per bucket — node hist, scan, row_ptr+dinv, csr scatter ----------
__global__ __launch_bounds__(256) void csr_finalize(
    const unsigned int* __restrict__ buf, const int* __restrict__ bbase,
    int* __restrict__ row_ptr, float* __restrict__ dinv,
    int* __restrict__ csr, int N, int E, int NB2) {
    __shared__ int hist[1 << SB2];        // 512
    __shared__ int excl[1 << SB2];
    __shared__ int ssc[256];
    int b = blockIdx.x, t = threadIdx.x;
    int nb0 = b << SB2;
    int nn = N - nb0; if (nn > (1 << SB2)) nn = 1 << SB2;
    int beg = bbase[b];
    int end = (b + 1 < NB2) ? bbase[b + 1] : E;

    hist[t] = 0; hist[t + 256] = 0;
    __syncthreads();
    for (int i = beg + t; i < end; i += 256)
        atomicAdd(&hist[buf[i] >> 23], 1);
    __syncthreads();

    int a0 = hist[2 * t], a1 = hist[2 * t + 1];
    int s = a0 + a1;
    ssc[t] = s;
    __syncthreads();
    for (int off = 1; off < 256; off <<= 1) {
        int x = (t >= off) ? ssc[t - off] : 0;
        __syncthreads();
        ssc[t] += x;
        __syncthreads();
    }
    int run = ssc[t] - s;
    excl[2 * t] = run;
    excl[2 * t + 1] = run + a0;
    __syncthreads();

    for (int j = t; j < nn; j += 256) {
        row_ptr[nb0 + j] = beg + excl[j];
        dinv[nb0 + j] = rsqrtf((float)hist[j] + 1.0f);   // +1 self-loop
    }
    if (b == NB2 - 1 && t == 0) row_ptr[N] = E;
    __syncthreads();

    hist[t] = 0; hist[t + 256] = 0;
    __syncthreads();
    for (int i = beg + t; i < end; i += 256) {
        unsigned int w = buf[i];
        int local = w >> 23;
        int p = beg + excl[local] + atomicAdd(&hist[local], 1);
        csr[p] = (int)(w & 0x7fffffu);
    }
}

// ---------- MFMA GEMM: hs(bf16, stride 64) = (A @ W) * d_inv[row] ----------
// Block: 64 rows x 64 cols, 4 waves x 16 rows. A: fp32 (layer1, converted
// in-register) or bf16 stride-64 (layers 2/3, direct 16B fragment loads).
// W staged transposed+zero-padded in LDS; epilogue via LDS for coalesced
// bf16 row stores with fused d_inv scale.
template<int K, int NOUT, bool AFP32>
__global__ __launch_bounds__(256) void gemm_mfma(
    const void* __restrict__ Aptr, const float* __restrict__ W,
    const float* __restrict__ d_inv, unsigned short* __restrict__ hs, int M)
{
    __shared__ unsigned short Wt[64][K + 8];   // [col][k], +8 pad: <=2-way LDS alias
    __shared__ float Cst[64][68];              // epilogue staging, 16B-aligned rows

    const int t = threadIdx.x;
    const int wave = t >> 6, lane = t & 63;
    const int m = lane & 15, kq = lane >> 4;   // frag row/col index, k-quad

    for (int idx = t; idx < K * 64; idx += 256) {
        int k = idx >> 6, c = idx & 63;
        float wv = (c < NOUT) ? W[k * NOUT + c] : 0.0f;
        Wt[c][k] = bf_rne(wv);
    }
    __syncthreads();

    const int rb = blockIdx.x * 64;            // block row base
    int arow = rb + wave * 16 + m;
    if (arow >= M) arow = M - 1;               // clamp (stores are guarded)

    f32x4 acc[4] = {{0.f,0.f,0.f,0.f},{0.f,0.f,0.f,0.f},
                    {0.f,0.f,0.f,0.f},{0.f,0.f,0.f,0.f}};
    union Frag { bf16x8 v; unsigned short u[8]; };

#pragma unroll
    for (int kc = 0; kc < K / 32; ++kc) {
        const int kbase = kc * 32 + kq * 8;
        Frag a;
        if (AFP32) {
            const float* ap = (const float*)Aptr + (size_t)arow * K + kbase;
            float4 x0 = *(const float4*)ap;
            float4 x1 = *(const float4*)(ap + 4);
            a.u[0] = bf_rne(x0.x); a.u[1] = bf_rne(x0.y);
            a.u[2] = bf_rne(x0.z); a.u[3] = bf_rne(x0.w);
            a.u[4] = bf_rne(x1.x); a.u[5] = bf_rne(x1.y);
            a.u[6] = bf_rne(x1.z); a.u[7] = bf_rne(x1.w);
        } else {
            const unsigned short* ap = (const unsigned short*)Aptr + (size_t)arow * 64 + kbase;
            a.v = *(const bf16x8*)ap;
        }
#pragma unroll
        for (int ct = 0; ct < 4; ++ct) {
            Frag b;
            b.v = *(const bf16x8*)(&Wt[ct * 16 + m][kbase]);
            acc[ct] = __builtin_amdgcn_mfma_f32_16x16x32_bf16(a.v, b.v, acc[ct], 0, 0, 0);
        }
    }

    // C/D layout: col = lane&15 (within ct tile), row = kq*4 + reg
#pragma unroll
    for (int ct = 0; ct < 4; ++ct)
#pragma unroll
        for (int r = 0; r < 4; ++r)
            Cst[wave * 16 + kq * 4 + r][ct * 16 + m] = acc[ct][r];
    __syncthreads();

    // epilogue: thread -> (row, 16-col segment); coalesced 32B bf16 stores
    int row = t >> 2, seg = t & 3;
    int grow = rb + row;
    if (grow < M) {
        float di = d_inv[grow];
        unsigned int uu[8];
#pragma unroll
        for (int j = 0; j < 8; ++j) {
            float v0 = Cst[row][seg * 16 + 2 * j]     * di;
            float v1 = Cst[row][seg * 16 + 2 * j + 1] * di;
            uu[j] = pk(bf_rne(v0), bf_rne(v1));
        }
        unsigned short* orow = hs + (size_t)grow * 64 + seg * 16;
        *(uint4*)orow       = make_uint4(uu[0], uu[1], uu[2], uu[3]);
        *((uint4*)orow + 1) = make_uint4(uu[4], uu[5], uu[6], uu[7]);
    }
}

// ---------- fused aggregate + epilogue ----------
// One wave/node. lane = g*8+q: g = edge subgroup (8 in flight), q = dim octet.
// OBF16: write bf16 activations (stride 64) for the next GEMM; else fp32 out.
template<int DACT, bool RELU, bool OBF16, int OSTRIDE>
__global__ __launch_bounds__(256) void agg8(
    const unsigned short* __restrict__ hs, const int* __restrict__ row_ptr,
    const int* __restrict__ csr, const float* __restrict__ dinv,
    const float* __restrict__ b, void* __restrict__ out, int N)
{
    int wave = (blockIdx.x * 256 + threadIdx.x) >> 6;
    int lane = threadIdx.x & 63;
    if (wave >= N) return;
    int i = wave;
    int g = lane >> 3, q = lane & 7;
    const uint4* hsv = (const uint4*)hs;      // row = 8 x uint4 (128B)

    int beg = row_ptr[i], end = row_ptr[i + 1];
    float acc[8] = {0.f, 0.f, 0.f, 0.f, 0.f, 0.f, 0.f, 0.f};

    for (int c = beg; c < end; c += 64) {
        int m = end - c; if (m > 64) m = 64;
        int s_l = (c + lane < end) ? csr[c + lane] : 0;
        int nIter = (m + 7) >> 3;
        for (int k = 0; k < nIter; ++k) {
            int ei = k * 8 + g;
            int s = __shfl(s_l, ei, 64);
            if (ei < m) {
                uint4 u = hsv[(size_t)s * 8 + q];
                acc[0] += __uint_as_float(u.x << 16);
                acc[1] += __uint_as_float(u.x & 0xffff0000u);
                acc[2] += __uint_as_float(u.y << 16);
                acc[3] += __uint_as_float(u.y & 0xffff0000u);
                acc[4] += __uint_as_float(u.z << 16);
                acc[5] += __uint_as_float(u.z & 0xffff0000u);
                acc[6] += __uint_as_float(u.w << 16);
                acc[7] += __uint_as_float(u.w & 0xffff0000u);
            }
        }
    }

#pragma unroll
    for (int off = 8; off < 64; off <<= 1)
#pragma unroll
        for (int j = 0; j < 8; ++j)
            acc[j] += __shfl_xor(acc[j], off, 64);

    if (g == 0 && q * 8 < DACT) {
        uint4 u = hsv[(size_t)i * 8 + q];                // self-loop row
        acc[0] += __uint_as_float(u.x << 16);
        acc[1] += __uint_as_float(u.x & 0xffff0000u);
        acc[2] += __uint_as_float(u.y << 16);
        acc[3] += __uint_as_float(u.y & 0xffff0000u);
        acc[4] += __uint_as_float(u.z << 16);
        acc[5] += __uint_as_float(u.z & 0xffff0000u);
        acc[6] += __uint_as_float(u.w << 16);
        acc[7] += __uint_as_float(u.w & 0xffff0000u);
        float di = dinv[i];
#pragma unroll
        for (int j = 0; j < 8; ++j) {
            acc[j] = di * acc[j] + b[q * 8 + j];
            if (RELU) acc[j] = fmaxf(acc[j], 0.0f);
        }
        if (OBF16) {
            unsigned short* ob = (unsigned short*)out;
            uint4 o;
            o.x = pk(bf_rne(acc[0]), bf_rne(acc[1]));
            o.y = pk(bf_rne(acc[2]), bf_rne(acc[3]));
            o.z = pk(bf_rne(acc[4]), bf_rne(acc[5]));
            o.w = pk(bf_rne(acc[6]), bf_rne(acc[7]));
            *(uint4*)(ob + (size_t)i * 64 + q * 8) = o;
        } else {
            float* of = (float*)out;
            *(float4*)(of + (size_t)i * OSTRIDE + q * 8) =
                make_float4(acc[0], acc[1], acc[2], acc[3]);
            *(float4*)(of + (size_t)i * OSTRIDE + q * 8 + 4) =
                make_float4(acc[4], acc[5], acc[6], acc[7]);
        }
    }
}

extern "C" void kernel_launch(void* const* d_in, const int* in_sizes, int n_in,
                              void* d_out, int out_size, void* d_ws, size_t ws_size,
                              hipStream_t stream) {
    const float* x   = (const float*)d_in[0];
    const int*   ei  = (const int*)  d_in[1];
    const float* W1  = (const float*)d_in[2];
    const float* bb1 = (const float*)d_in[3];
    const float* W2  = (const float*)d_in[4];
    const float* bb2 = (const float*)d_in[5];
    const float* W3  = (const float*)d_in[6];
    const float* bb3 = (const float*)d_in[7];
    float* out = (float*)d_out;

    const int N = in_sizes[0] / 128;      // 100000
    const int E = in_sizes[1] / 2;        // 1600000
    const int* src = ei;
    const int* dst = ei + E;
    const int NB2  = (N + (1 << SB2) - 1) >> SB2;   // 196 buckets (<=256)
    const int nblk = (E + EPB - 1) / EPB;           // 391 partition blocks (<=1024)

    // workspace layout (4-byte units)
    float* ws = (float*)d_ws;
    const size_t NP  = ((size_t)N + 255) & ~255ull;
    float* dinv = ws;                                   // NP
    unsigned short* bufHs  = (unsigned short*)(ws + NP);        // N*64 bf16
    unsigned short* bufAct = bufHs + (size_t)N * 64;            // N*64 bf16
    int*   row_ptr = (int*)(bufAct + (size_t)N * 64);   // N+1 (pad to even)
    int*   btot    = row_ptr + (((size_t)N + 2) & ~1ull);  // 256
    int*   bbase   = btot + 256;                        // 256
    int*   bh      = bbase + 256;                       // NB2*nblk (pad even)
    size_t bhsz    = ((size_t)NB2 * nblk + 1) & ~1ull;
    unsigned int* buf = (unsigned int*)(bh + bhsz);     // E packed words
    int*   csr     = (int*)(buf + E);                   // E

    dim3 blk(BLK);
    int gRows = (N + 63) / 64;
    int gWave = (N * 64 + BLK - 1) / BLK;    // one wave per node

    // ---- binned partition -> CSR + degrees (no global histogram) ----
    part_hist<<<nblk, blk, 0, stream>>>(dst, bh, E, nblk, NB2);
    bucket_totals<<<NB2, blk, 0, stream>>>(bh, btot, nblk);
    bucket_scan<<<1, blk, 0, stream>>>(btot, bbase, NB2);
    part_scan<<<NB2, blk, 0, stream>>>(bh, bbase, nblk);
    part_scatter<<<nblk, blk, 0, stream>>>(src, dst, bh, buf, E, nblk, NB2);
    csr_finalize<<<NB2, blk, 0, stream>>>(buf, bbase, row_ptr, dinv, csr, N, E, NB2);

    // ---- layer 1: 128 -> 64, relu ----
    gemm_mfma<128, 64, true><<<gRows, blk, 0, stream>>>(x, W1, dinv, bufHs, N);
    agg8<64, true, true, 64><<<gWave, blk, 0, stream>>>(bufHs, row_ptr, csr, dinv, bb1, bufAct, N);

    // ---- layer 2: 64 -> 64, relu ----
    gemm_mfma<64, 64, false><<<gRows, blk, 0, stream>>>(bufAct, W2, dinv, bufHs, N);
    agg8<64, true, true, 64><<<gWave, blk, 0, stream>>>(bufHs, row_ptr, csr, dinv, bb2, bufAct, N);

    // ---- layer 3: 64 -> 40 (bf16 rows zero-padded to 64), no relu ----
    gemm_mfma<64, 40, false><<<gRows, blk, 0, stream>>>(bufAct, W3, dinv, bufHs, N);
    agg8<40, false, false, 40><<<gWave, blk, 0, stream>>>(bufHs, row_ptr, csr, dinv, bb3, out, N);
}

// Round 8
// 319.061 us; speedup vs baseline: 2.4162x; 1.0213x over previous
//
#include <hip/hip_runtime.h>
#include <hip/hip_bf16.h>

// GCN 3-layer. CSR via LDS-binned partition. bf16 MFMA GEMM + bf16 gather.
//   hs(bf16) = (A@W) * d_inv[row]   (fused scale)
//   out_i = act(d_inv[i]*(hs_i + sum_{e:dst=i} hs[src_e]) + b)
//     agg4: quarter-wave per node, lane owns 4 dims -> no cross-lane reduce.

constexpr int BLK = 256;
constexpr int SB2 = 9;                  // bucket = 512 nodes
constexpr int EPB = 4096;               // edges per partition block
// packed partition word: (local_node_id << 23) | src   (requires N < 2^23)

typedef __attribute__((ext_vector_type(8))) short bf16x8;   // 8 bf16 = 4 VGPR
typedef __attribute__((ext_vector_type(4))) float f32x4;    // MFMA acc

__device__ inline unsigned short bf_rne(float f) {
    unsigned int u = __float_as_uint(f);
    unsigned int r = (u + 0x7fffu + ((u >> 16) & 1u)) >> 16;
    return (unsigned short)r;
}
__device__ inline unsigned int pk(unsigned short lo, unsigned short hi) {
    return (unsigned int)lo | ((unsigned int)hi << 16);
}

// ---------- Pass A: per-block histogram of dst>>SB2 ----------
__global__ __launch_bounds__(256) void part_hist(
    const int* __restrict__ dst, int* __restrict__ bh, int E, int nblk, int NB2) {
    __shared__ int lh[256];               // NB2 <= 256
    int k = blockIdx.x, t = threadIdx.x;
    lh[t] = 0;
    __syncthreads();
    int e0 = k * EPB;
#pragma unroll
    for (int j = 0; j < EPB / 256; ++j) {
        int e = e0 + j * 256 + t;
        if (e < E) atomicAdd(&lh[dst[e] >> SB2], 1);
    }
    __syncthreads();
    if (t < NB2) bh[t * nblk + k] = lh[t];
}

// ---------- bucket totals: btot[b] = sum_k bh[b][k] ----------
__global__ __launch_bounds__(256) void bucket_totals(
    const int* __restrict__ bh, int* __restrict__ btot, int nblk) {
    __shared__ int sh[256];
    int b = blockIdx.x, t = threadIdx.x;
    int s = 0;
    for (int i = t; i < nblk; i += 256) s += bh[b * nblk + i];
    sh[t] = s;
    __syncthreads();
    for (int off = 128; off > 0; off >>= 1) {
        if (t < off) sh[t] += sh[t + off];
        __syncthreads();
    }
    if (t == 0) btot[b] = sh[0];
}

// ---------- bucket base: exclusive scan of btot (NB2 <= 256) ----------
__global__ void bucket_scan(const int* __restrict__ btot, int* __restrict__ bbase, int NB2) {
    __shared__ int sh[256];
    int t = threadIdx.x;
    int v = (t < NB2) ? btot[t] : 0;
    sh[t] = v;
    __syncthreads();
    for (int off = 1; off < 256; off <<= 1) {
        int x = (t >= off) ? sh[t - off] : 0;
        __syncthreads();
        sh[t] += x;
        __syncthreads();
    }
    if (t < NB2) bbase[t] = sh[t] - v;
}

// ---------- Pass A': per bucket, exclusive scan over blocks + bucket base ----------
__global__ __launch_bounds__(256) void part_scan(
    int* __restrict__ bh, const int* __restrict__ bbase, int nblk) {
    __shared__ int sh[256];
    int b = blockIdx.x, t = threadIdx.x;
    int base = bbase[b];
    int v[4]; int s = 0;                  // supports nblk <= 1024
#pragma unroll
    for (int j = 0; j < 4; ++j) {
        int idx = t * 4 + j;
        v[j] = (idx < nblk) ? bh[b * nblk + idx] : 0;
        s += v[j];
    }
    sh[t] = s;
    __syncthreads();
    for (int off = 1; off < 256; off <<= 1) {
        int x = (t >= off) ? sh[t - off] : 0;
        __syncthreads();
        sh[t] += x;
        __syncthreads();
    }
    int run = sh[t] - s;
#pragma unroll
    for (int j = 0; j < 4; ++j) {
        int idx = t * 4 + j;
        if (idx < nblk) bh[b * nblk + idx] = base + run;
        run += v[j];
    }
}

// ---------- Pass B: scatter packed (local,src) into private (block,bucket) runs ----------
__global__ __launch_bounds__(256) void part_scatter(
    const int* __restrict__ src, const int* __restrict__ dst,
    const int* __restrict__ bh, unsigned int* __restrict__ buf,
    int E, int nblk, int NB2) {
    __shared__ int lbase[256];
    __shared__ int lcnt[256];
    int k = blockIdx.x, t = threadIdx.x;
    lcnt[t] = 0;
    if (t < NB2) lbase[t] = bh[t * nblk + k];
    __syncthreads();
    int e0 = k * EPB;
#pragma unroll
    for (int j = 0; j < EPB / 256; ++j) {
        int e = e0 + j * 256 + t;
        if (e < E) {
            int d = dst[e];
            int b = d >> SB2;
            int p = lbase[b] + atomicAdd(&lcnt[b], 1);
            buf[p] = ((unsigned int)(d & ((1 << SB2) - 1)) << 23) | (unsigned int)src[e];
        }
    }
}

// ---------- Pass C: per bucket — node hist, scan, row_ptr+dinv, csr scatter ----------
__global__ __launch_bounds__(256) void csr_finalize(
    const unsigned int* __restrict__ buf, const int* __restrict__ bbase,
    int* __restrict__ row_ptr, float* __restrict__ dinv,
    int* __restrict__ csr, int N, int E, int NB2) {
    __shared__ int hist[1 << SB2];        // 512
    __shared__ int excl[1 << SB2];
    __shared__ int ssc[256];
    int b = blockIdx.x, t = threadIdx.x;
    int nb0 = b << SB2;
    int nn = N - nb0; if (nn > (1 << SB2)) nn = 1 << SB2;
    int beg = bbase[b];
    int end = (b + 1 < NB2) ? bbase[b + 1] : E;

    hist[t] = 0; hist[t + 256] = 0;
    __syncthreads();
    for (int i = beg + t; i < end; i += 256)
        atomicAdd(&hist[buf[i] >> 23], 1);
    __syncthreads();

    int a0 = hist[2 * t], a1 = hist[2 * t + 1];
    int s = a0 + a1;
    ssc[t] = s;
    __syncthreads();
    for (int off = 1; off < 256; off <<= 1) {
        int x = (t >= off) ? ssc[t - off] : 0;
        __syncthreads();
        ssc[t] += x;
        __syncthreads();
    }
    int run = ssc[t] - s;
    excl[2 * t] = run;
    excl[2 * t + 1] = run + a0;
    __syncthreads();

    for (int j = t; j < nn; j += 256) {
        row_ptr[nb0 + j] = beg + excl[j];
        dinv[nb0 + j] = rsqrtf((float)hist[j] + 1.0f);   // +1 self-loop
    }
    if (b == NB2 - 1 && t == 0) row_ptr[N] = E;
    __syncthreads();

    hist[t] = 0; hist[t + 256] = 0;
    __syncthreads();
    for (int i = beg + t; i < end; i += 256) {
        unsigned int w = buf[i];
        int local = w >> 23;
        int p = beg + excl[local] + atomicAdd(&hist[local], 1);
        csr[p] = (int)(w & 0x7fffffu);
    }
}

// ---------- MFMA GEMM: hs(bf16, stride 64) = (A @ W) * d_inv[row] ----------
template<int K, int NOUT, bool AFP32>
__global__ __launch_bounds__(256) void gemm_mfma(
    const void* __restrict__ Aptr, const float* __restrict__ W,
    const float* __restrict__ d_inv, unsigned short* __restrict__ hs, int M)
{
    __shared__ unsigned short Wt[64][K + 8];   // [col][k], +8 pad: <=2-way LDS alias
    __shared__ float Cst[64][68];              // epilogue staging

    const int t = threadIdx.x;
    const int wave = t >> 6, lane = t & 63;
    const int m = lane & 15, kq = lane >> 4;

    for (int idx = t; idx < K * 64; idx += 256) {
        int k = idx >> 6, c = idx & 63;
        float wv = (c < NOUT) ? W[k * NOUT + c] : 0.0f;
        Wt[c][k] = bf_rne(wv);
    }
    __syncthreads();

    const int rb = blockIdx.x * 64;
    int arow = rb + wave * 16 + m;
    if (arow >= M) arow = M - 1;               // clamp (stores are guarded)

    f32x4 acc[4] = {{0.f,0.f,0.f,0.f},{0.f,0.f,0.f,0.f},
                    {0.f,0.f,0.f,0.f},{0.f,0.f,0.f,0.f}};
    union Frag { bf16x8 v; unsigned short u[8]; };

#pragma unroll
    for (int kc = 0; kc < K / 32; ++kc) {
        const int kbase = kc * 32 + kq * 8;
        Frag a;
        if (AFP32) {
            const float* ap = (const float*)Aptr + (size_t)arow * K + kbase;
            float4 x0 = *(const float4*)ap;
            float4 x1 = *(const float4*)(ap + 4);
            a.u[0] = bf_rne(x0.x); a.u[1] = bf_rne(x0.y);
            a.u[2] = bf_rne(x0.z); a.u[3] = bf_rne(x0.w);
            a.u[4] = bf_rne(x1.x); a.u[5] = bf_rne(x1.y);
            a.u[6] = bf_rne(x1.z); a.u[7] = bf_rne(x1.w);
        } else {
            const unsigned short* ap = (const unsigned short*)Aptr + (size_t)arow * 64 + kbase;
            a.v = *(const bf16x8*)ap;
        }
#pragma unroll
        for (int ct = 0; ct < 4; ++ct) {
            Frag b;
            b.v = *(const bf16x8*)(&Wt[ct * 16 + m][kbase]);
            acc[ct] = __builtin_amdgcn_mfma_f32_16x16x32_bf16(a.v, b.v, acc[ct], 0, 0, 0);
        }
    }

#pragma unroll
    for (int ct = 0; ct < 4; ++ct)
#pragma unroll
        for (int r = 0; r < 4; ++r)
            Cst[wave * 16 + kq * 4 + r][ct * 16 + m] = acc[ct][r];
    __syncthreads();

    int row = t >> 2, seg = t & 3;
    int grow = rb + row;
    if (grow < M) {
        float di = d_inv[grow];
        unsigned int uu[8];
#pragma unroll
        for (int j = 0; j < 8; ++j) {
            float v0 = Cst[row][seg * 16 + 2 * j]     * di;
            float v1 = Cst[row][seg * 16 + 2 * j + 1] * di;
            uu[j] = pk(bf_rne(v0), bf_rne(v1));
        }
        unsigned short* orow = hs + (size_t)grow * 64 + seg * 16;
        *(uint4*)orow       = make_uint4(uu[0], uu[1], uu[2], uu[3]);
        *((uint4*)orow + 1) = make_uint4(uu[4], uu[5], uu[6], uu[7]);
    }
}

// ---------- fused aggregate + epilogue: quarter-wave per node ----------
// lane = sub*16 + q: sub = node subgroup (4 nodes/wave), q = dim quad.
// Each lane owns dims [q*4, q*4+4) -> accumulates privately, NO reduce.
template<int DACT, bool RELU, bool OBF16, int OSTRIDE>
__global__ __launch_bounds__(256) void agg4(
    const unsigned short* __restrict__ hs, const int* __restrict__ row_ptr,
    const int* __restrict__ csr, const float* __restrict__ dinv,
    const float* __restrict__ b, void* __restrict__ out, int N)
{
    int i = (blockIdx.x * 256 + threadIdx.x) >> 4;     // node per quarter-wave
    if (i >= N) return;
    int lane = threadIdx.x & 63;
    int q  = lane & 15;                                 // dim quad
    int sb = lane & 48;                                 // subgroup base lane

    int beg = row_ptr[i], end = row_ptr[i + 1];

    // self-loop init
    uint2 u0 = *(const uint2*)(hs + (size_t)i * 64 + q * 4);
    float a0 = __uint_as_float(u0.x << 16);
    float a1 = __uint_as_float(u0.x & 0xffff0000u);
    float a2 = __uint_as_float(u0.y << 16);
    float a3 = __uint_as_float(u0.y & 0xffff0000u);

    for (int c = beg; c < end; c += 16) {
        int s_l = (c + q < end) ? csr[c + q] : 0;      // coalesced 64B prefetch
        int m = end - c; if (m > 16) m = 16;
        for (int k = 0; k < m; ++k) {
            int s = __shfl(s_l, sb | k, 64);
            uint2 u = *(const uint2*)(hs + (size_t)s * 64 + q * 4);
            a0 += __uint_as_float(u.x << 16);
            a1 += __uint_as_float(u.x & 0xffff0000u);
            a2 += __uint_as_float(u.y << 16);
            a3 += __uint_as_float(u.y & 0xffff0000u);
        }
    }

    if (q * 4 < DACT) {
        float di = dinv[i];
        const float4 bv = *(const float4*)(b + q * 4);
        a0 = di * a0 + bv.x; a1 = di * a1 + bv.y;
        a2 = di * a2 + bv.z; a3 = di * a3 + bv.w;
        if (RELU) {
            a0 = fmaxf(a0, 0.f); a1 = fmaxf(a1, 0.f);
            a2 = fmaxf(a2, 0.f); a3 = fmaxf(a3, 0.f);
        }
        if (OBF16) {
            unsigned short* ob = (unsigned short*)out;
            uint2 o;
            o.x = pk(bf_rne(a0), bf_rne(a1));
            o.y = pk(bf_rne(a2), bf_rne(a3));
            *(uint2*)(ob + (size_t)i * 64 + q * 4) = o;
        } else {
            float* of = (float*)out;
            *(float4*)(of + (size_t)i * OSTRIDE + q * 4) = make_float4(a0, a1, a2, a3);
        }
    }
}

extern "C" void kernel_launch(void* const* d_in, const int* in_sizes, int n_in,
                              void* d_out, int out_size, void* d_ws, size_t ws_size,
                              hipStream_t stream) {
    const float* x   = (const float*)d_in[0];
    const int*   ei  = (const int*)  d_in[1];
    const float* W1  = (const float*)d_in[2];
    const float* bb1 = (const float*)d_in[3];
    const float* W2  = (const float*)d_in[4];
    const float* bb2 = (const float*)d_in[5];
    const float* W3  = (const float*)d_in[6];
    const float* bb3 = (const float*)d_in[7];
    float* out = (float*)d_out;

    const int N = in_sizes[0] / 128;      // 100000
    const int E = in_sizes[1] / 2;        // 1600000
    const int* src = ei;
    const int* dst = ei + E;
    const int NB2  = (N + (1 << SB2) - 1) >> SB2;   // 196 buckets (<=256)
    const int nblk = (E + EPB - 1) / EPB;           // 391 partition blocks (<=1024)

    // workspace layout (4-byte units)
    float* ws = (float*)d_ws;
    const size_t NP  = ((size_t)N + 255) & ~255ull;
    float* dinv = ws;                                   // NP
    unsigned short* bufHs  = (unsigned short*)(ws + NP);        // N*64 bf16
    unsigned short* bufAct = bufHs + (size_t)N * 64;            // N*64 bf16
    int*   row_ptr = (int*)(bufAct + (size_t)N * 64);   // N+1 (pad to even)
    int*   btot    = row_ptr + (((size_t)N + 2) & ~1ull);  // 256
    int*   bbase   = btot + 256;                        // 256
    int*   bh      = bbase + 256;                       // NB2*nblk (pad even)
    size_t bhsz    = ((size_t)NB2 * nblk + 1) & ~1ull;
    unsigned int* buf = (unsigned int*)(bh + bhsz);     // E packed words
    int*   csr     = (int*)(buf + E);                   // E

    dim3 blk(BLK);
    int gRows = (N + 63) / 64;
    int gQW   = (N * 16 + BLK - 1) / BLK;    // quarter-wave per node

    // ---- binned partition -> CSR + degrees (no global histogram) ----
    part_hist<<<nblk, blk, 0, stream>>>(dst, bh, E, nblk, NB2);
    bucket_totals<<<NB2, blk, 0, stream>>>(bh, btot, nblk);
    bucket_scan<<<1, blk, 0, stream>>>(btot, bbase, NB2);
    part_scan<<<NB2, blk, 0, stream>>>(bh, bbase, nblk);
    part_scatter<<<nblk, blk, 0, stream>>>(src, dst, bh, buf, E, nblk, NB2);
    csr_finalize<<<NB2, blk, 0, stream>>>(buf, bbase, row_ptr, dinv, csr, N, E, NB2);

    // ---- layer 1: 128 -> 64, relu ----
    gemm_mfma<128, 64, true><<<gRows, blk, 0, stream>>>(x, W1, dinv, bufHs, N);
    agg4<64, true, true, 64><<<gQW, blk, 0, stream>>>(bufHs, row_ptr, csr, dinv, bb1, bufAct, N);

    // ---- layer 2: 64 -> 64, relu ----
    gemm_mfma<64, 64, false><<<gRows, blk, 0, stream>>>(bufAct, W2, dinv, bufHs, N);
    agg4<64, true, true, 64><<<gQW, blk, 0, stream>>>(bufHs, row_ptr, csr, dinv, bb2, bufAct, N);

    // ---- layer 3: 64 -> 40 (bf16 rows zero-padded to 64), no relu ----
    gemm_mfma<64, 40, false><<<gRows, blk, 0, stream>>>(bufAct, W3, dinv, bufHs, N);
    agg4<40, false, false, 40><<<gQW, blk, 0, stream>>>(bufHs, row_ptr, csr, dinv, bb3, out, N);
}

// Round 9
// 287.506 us; speedup vs baseline: 2.6814x; 1.1098x over previous
//
#include <hip/hip_runtime.h>
#include <hip/hip_bf16.h>

// GCN 3-layer. CSR via LDS-binned partition into fixed-capacity bucket
// windows (base = b*BUCKCAP -> no global scan chain). bf16 MFMA GEMM +
// bf16 gather with 8-deep load batching (memory-latency hiding).
//   hs(bf16) = (A@W) * d_inv[row]
//   out_i = act(d_inv[i]*(hs_i + sum_{e:dst=i} hs[src_e]) + b)

constexpr int BLK = 256;
constexpr int SB2 = 9;                  // bucket = 512 nodes
constexpr int EPB = 4096;               // edges per partition block
constexpr int BUCKCAP = 10240;          // bucket window capacity (mean 8192, +22 sigma)
// packed partition word: (local_node_id << 23) | src   (requires N < 2^23)

typedef __attribute__((ext_vector_type(8))) short bf16x8;   // 8 bf16 = 4 VGPR
typedef __attribute__((ext_vector_type(4))) float f32x4;    // MFMA acc

__device__ inline unsigned short bf_rne(float f) {
    unsigned int u = __float_as_uint(f);
    unsigned int r = (u + 0x7fffu + ((u >> 16) & 1u)) >> 16;
    return (unsigned short)r;
}
__device__ inline unsigned int pk(unsigned short lo, unsigned short hi) {
    return (unsigned int)lo | ((unsigned int)hi << 16);
}

// ---------- Pass A: per-block histogram of dst>>SB2 (int4 reads) ----------
__global__ __launch_bounds__(256) void part_hist(
    const int* __restrict__ dst, int* __restrict__ bh, int E, int nblk, int NB2) {
    __shared__ int lh[256];               // NB2 <= 256
    int k = blockIdx.x, t = threadIdx.x;
    lh[t] = 0;
    __syncthreads();
    const int4* dp = (const int4*)(dst + k * EPB);
#pragma unroll
    for (int j = 0; j < EPB / 1024; ++j) {
        int idx = j * 256 + t;            // int4 index within block
        int e = k * EPB + idx * 4;
        if (e < E) {                      // E % 4 == 0 -> whole int4 valid
            int4 d4 = dp[idx];
            atomicAdd(&lh[d4.x >> SB2], 1);
            atomicAdd(&lh[d4.y >> SB2], 1);
            atomicAdd(&lh[d4.z >> SB2], 1);
            atomicAdd(&lh[d4.w >> SB2], 1);
        }
    }
    __syncthreads();
    if (t < NB2) bh[t * nblk + k] = lh[t];
}

// ---------- Pass A': per bucket, exclusive scan over blocks; base = b*BUCKCAP ----------
__global__ __launch_bounds__(256) void part_scan(
    int* __restrict__ bh, int* __restrict__ btot, int nblk) {
    __shared__ int sh[256];
    int b = blockIdx.x, t = threadIdx.x;
    int base = b * BUCKCAP;
    int v[4]; int s = 0;                  // supports nblk <= 1024
#pragma unroll
    for (int j = 0; j < 4; ++j) {
        int idx = t * 4 + j;
        v[j] = (idx < nblk) ? bh[b * nblk + idx] : 0;
        s += v[j];
    }
    sh[t] = s;
    __syncthreads();
    for (int off = 1; off < 256; off <<= 1) {
        int x = (t >= off) ? sh[t - off] : 0;
        __syncthreads();
        sh[t] += x;
        __syncthreads();
    }
    int run = sh[t] - s;
    if (t == 255) btot[b] = (sh[255] < BUCKCAP) ? sh[255] : BUCKCAP;  // safety clamp
#pragma unroll
    for (int j = 0; j < 4; ++j) {
        int idx = t * 4 + j;
        if (idx < nblk) bh[b * nblk + idx] = base + run;
        run += v[j];
    }
}

// ---------- Pass B: scatter packed (local,src) into private (block,bucket) runs ----------
__global__ __launch_bounds__(256) void part_scatter(
    const int* __restrict__ src, const int* __restrict__ dst,
    const int* __restrict__ bh, unsigned int* __restrict__ buf,
    int E, int nblk, int NB2) {
    __shared__ int lbase[256];
    __shared__ int lcnt[256];
    int k = blockIdx.x, t = threadIdx.x;
    lcnt[t] = 0;
    if (t < NB2) lbase[t] = bh[t * nblk + k];
    __syncthreads();
    const int4* dp = (const int4*)(dst + k * EPB);
    const int4* sp = (const int4*)(src + k * EPB);
#pragma unroll
    for (int j = 0; j < EPB / 1024; ++j) {
        int idx = j * 256 + t;
        int e = k * EPB + idx * 4;
        if (e < E) {
            int4 d4 = dp[idx];
            int4 s4 = sp[idx];
            int d, bkt, p;
            d = d4.x; bkt = d >> SB2; p = lbase[bkt] + atomicAdd(&lcnt[bkt], 1);
            buf[p] = ((unsigned int)(d & 511) << 23) | (unsigned int)s4.x;
            d = d4.y; bkt = d >> SB2; p = lbase[bkt] + atomicAdd(&lcnt[bkt], 1);
            buf[p] = ((unsigned int)(d & 511) << 23) | (unsigned int)s4.y;
            d = d4.z; bkt = d >> SB2; p = lbase[bkt] + atomicAdd(&lcnt[bkt], 1);
            buf[p] = ((unsigned int)(d & 511) << 23) | (unsigned int)s4.z;
            d = d4.w; bkt = d >> SB2; p = lbase[bkt] + atomicAdd(&lcnt[bkt], 1);
            buf[p] = ((unsigned int)(d & 511) << 23) | (unsigned int)s4.w;
        }
    }
}

// ---------- Pass C: per bucket — node hist, scan, rptr/rdeg/dinv, csr scatter ----------
__global__ __launch_bounds__(256) void csr_finalize(
    const unsigned int* __restrict__ buf, const int* __restrict__ btot,
    int* __restrict__ rptr, int* __restrict__ rdeg, float* __restrict__ dinv,
    int* __restrict__ csr, int N) {
    __shared__ int hist[1 << SB2];        // 512
    __shared__ int excl[1 << SB2];
    __shared__ int ssc[256];
    int b = blockIdx.x, t = threadIdx.x;
    int nb0 = b << SB2;
    int nn = N - nb0; if (nn > (1 << SB2)) nn = 1 << SB2;
    int beg = b * BUCKCAP;
    int end = beg + btot[b];

    hist[t] = 0; hist[t + 256] = 0;
    __syncthreads();
    for (int i = beg + t; i < end; i += 256)
        atomicAdd(&hist[buf[i] >> 23], 1);
    __syncthreads();

    int a0 = hist[2 * t], a1 = hist[2 * t + 1];
    int s = a0 + a1;
    ssc[t] = s;
    __syncthreads();
    for (int off = 1; off < 256; off <<= 1) {
        int x = (t >= off) ? ssc[t - off] : 0;
        __syncthreads();
        ssc[t] += x;
        __syncthreads();
    }
    int run = ssc[t] - s;
    excl[2 * t] = run;
    excl[2 * t + 1] = run + a0;
    __syncthreads();

    for (int j = t; j < nn; j += 256) {
        rptr[nb0 + j] = beg + excl[j];
        rdeg[nb0 + j] = hist[j];
        dinv[nb0 + j] = rsqrtf((float)hist[j] + 1.0f);   // +1 self-loop
    }
    __syncthreads();

    hist[t] = 0; hist[t + 256] = 0;
    __syncthreads();
    for (int i = beg + t; i < end; i += 256) {
        unsigned int w = buf[i];
        int local = w >> 23;
        int p = beg + excl[local] + atomicAdd(&hist[local], 1);
        csr[p] = (int)(w & 0x7fffffu);
    }
}

// ---------- MFMA GEMM: hs(bf16, stride 64) = (A @ W) * d_inv[row] ----------
template<int K, int NOUT, bool AFP32>
__global__ __launch_bounds__(256) void gemm_mfma(
    const void* __restrict__ Aptr, const float* __restrict__ W,
    const float* __restrict__ d_inv, unsigned short* __restrict__ hs, int M)
{
    __shared__ unsigned short Wt[64][K + 8];   // [col][k], +8 pad: <=2-way LDS alias
    __shared__ float Cst[64][68];              // epilogue staging

    const int t = threadIdx.x;
    const int wave = t >> 6, lane = t & 63;
    const int m = lane & 15, kq = lane >> 4;

    for (int idx = t; idx < K * 64; idx += 256) {
        int k = idx >> 6, c = idx & 63;
        float wv = (c < NOUT) ? W[k * NOUT + c] : 0.0f;
        Wt[c][k] = bf_rne(wv);
    }
    __syncthreads();

    const int rb = blockIdx.x * 64;
    int arow = rb + wave * 16 + m;
    if (arow >= M) arow = M - 1;               // clamp (stores are guarded)

    f32x4 acc[4] = {{0.f,0.f,0.f,0.f},{0.f,0.f,0.f,0.f},
                    {0.f,0.f,0.f,0.f},{0.f,0.f,0.f,0.f}};
    union Frag { bf16x8 v; unsigned short u[8]; };

#pragma unroll
    for (int kc = 0; kc < K / 32; ++kc) {
        const int kbase = kc * 32 + kq * 8;
        Frag a;
        if (AFP32) {
            const float* ap = (const float*)Aptr + (size_t)arow * K + kbase;
            float4 x0 = *(const float4*)ap;
            float4 x1 = *(const float4*)(ap + 4);
            a.u[0] = bf_rne(x0.x); a.u[1] = bf_rne(x0.y);
            a.u[2] = bf_rne(x0.z); a.u[3] = bf_rne(x0.w);
            a.u[4] = bf_rne(x1.x); a.u[5] = bf_rne(x1.y);
            a.u[6] = bf_rne(x1.z); a.u[7] = bf_rne(x1.w);
        } else {
            const unsigned short* ap = (const unsigned short*)Aptr + (size_t)arow * 64 + kbase;
            a.v = *(const bf16x8*)ap;
        }
#pragma unroll
        for (int ct = 0; ct < 4; ++ct) {
            Frag b;
            b.v = *(const bf16x8*)(&Wt[ct * 16 + m][kbase]);
            acc[ct] = __builtin_amdgcn_mfma_f32_16x16x32_bf16(a.v, b.v, acc[ct], 0, 0, 0);
        }
    }

#pragma unroll
    for (int ct = 0; ct < 4; ++ct)
#pragma unroll
        for (int r = 0; r < 4; ++r)
            Cst[wave * 16 + kq * 4 + r][ct * 16 + m] = acc[ct][r];
    __syncthreads();

    int row = t >> 2, seg = t & 3;
    int grow = rb + row;
    if (grow < M) {
        float di = d_inv[grow];
        unsigned int uu[8];
#pragma unroll
        for (int j = 0; j < 8; ++j) {
            float v0 = Cst[row][seg * 16 + 2 * j]     * di;
            float v1 = Cst[row][seg * 16 + 2 * j + 1] * di;
            uu[j] = pk(bf_rne(v0), bf_rne(v1));
        }
        unsigned short* orow = hs + (size_t)grow * 64 + seg * 16;
        *(uint4*)orow       = make_uint4(uu[0], uu[1], uu[2], uu[3]);
        *((uint4*)orow + 1) = make_uint4(uu[4], uu[5], uu[6], uu[7]);
    }
}

// ---------- fused aggregate + epilogue: quarter-wave per node ----------
// lane = sub*16 + q. Lane owns dims [q*4, q*4+4): private accumulate, no
// reduce. Gather batched 8-deep: 8 independent loads in flight per lane.
template<int DACT, bool RELU, bool OBF16, int OSTRIDE>
__global__ __launch_bounds__(256) void agg4(
    const unsigned short* __restrict__ hs, const int* __restrict__ rptr,
    const int* __restrict__ rdeg, const int* __restrict__ csr,
    const float* __restrict__ dinv, const float* __restrict__ b,
    void* __restrict__ out, int N)
{
    int i = (blockIdx.x * 256 + threadIdx.x) >> 4;     // node per quarter-wave
    if (i >= N) return;
    int lane = threadIdx.x & 63;
    int q  = lane & 15;                                 // dim quad
    int sb = lane & 48;                                 // subgroup base lane

    int beg = rptr[i];
    int end = beg + rdeg[i];

    // self-loop init
    uint2 u0 = *(const uint2*)(hs + (size_t)i * 64 + q * 4);
    float a0 = __uint_as_float(u0.x << 16);
    float a1 = __uint_as_float(u0.x & 0xffff0000u);
    float a2 = __uint_as_float(u0.y << 16);
    float a3 = __uint_as_float(u0.y & 0xffff0000u);

    for (int c = beg; c < end; c += 16) {
        int s_l = (c + q < end) ? csr[c + q] : 0;      // coalesced 64B prefetch
        int m = end - c; if (m > 16) m = 16;
        int k = 0;
        for (; k + 8 <= m; k += 8) {                   // 8 loads in flight
            int ss[8];
#pragma unroll
            for (int j = 0; j < 8; ++j) ss[j] = __shfl(s_l, sb | (k + j), 64);
            uint2 vv[8];
#pragma unroll
            for (int j = 0; j < 8; ++j)
                vv[j] = *(const uint2*)(hs + (size_t)ss[j] * 64 + q * 4);
#pragma unroll
            for (int j = 0; j < 8; ++j) {
                a0 += __uint_as_float(vv[j].x << 16);
                a1 += __uint_as_float(vv[j].x & 0xffff0000u);
                a2 += __uint_as_float(vv[j].y << 16);
                a3 += __uint_as_float(vv[j].y & 0xffff0000u);
            }
        }
        for (; k < m; ++k) {
            int s = __shfl(s_l, sb | k, 64);
            uint2 u = *(const uint2*)(hs + (size_t)s * 64 + q * 4);
            a0 += __uint_as_float(u.x << 16);
            a1 += __uint_as_float(u.x & 0xffff0000u);
            a2 += __uint_as_float(u.y << 16);
            a3 += __uint_as_float(u.y & 0xffff0000u);
        }
    }

    if (q * 4 < DACT) {
        float di = dinv[i];
        const float4 bv = *(const float4*)(b + q * 4);
        a0 = di * a0 + bv.x; a1 = di * a1 + bv.y;
        a2 = di * a2 + bv.z; a3 = di * a3 + bv.w;
        if (RELU) {
            a0 = fmaxf(a0, 0.f); a1 = fmaxf(a1, 0.f);
            a2 = fmaxf(a2, 0.f); a3 = fmaxf(a3, 0.f);
        }
        if (OBF16) {
            unsigned short* ob = (unsigned short*)out;
            uint2 o;
            o.x = pk(bf_rne(a0), bf_rne(a1));
            o.y = pk(bf_rne(a2), bf_rne(a3));
            *(uint2*)(ob + (size_t)i * 64 + q * 4) = o;
        } else {
            float* of = (float*)out;
            *(float4*)(of + (size_t)i * OSTRIDE + q * 4) = make_float4(a0, a1, a2, a3);
        }
    }
}

extern "C" void kernel_launch(void* const* d_in, const int* in_sizes, int n_in,
                              void* d_out, int out_size, void* d_ws, size_t ws_size,
                              hipStream_t stream) {
    const float* x   = (const float*)d_in[0];
    const int*   ei  = (const int*)  d_in[1];
    const float* W1  = (const float*)d_in[2];
    const float* bb1 = (const float*)d_in[3];
    const float* W2  = (const float*)d_in[4];
    const float* bb2 = (const float*)d_in[5];
    const float* W3  = (const float*)d_in[6];
    const float* bb3 = (const float*)d_in[7];
    float* out = (float*)d_out;

    const int N = in_sizes[0] / 128;      // 100000
    const int E = in_sizes[1] / 2;        // 1600000
    const int* src = ei;
    const int* dst = ei + E;
    const int NB2  = (N + (1 << SB2) - 1) >> SB2;   // 196 buckets (<=256)
    const int nblk = (E + EPB - 1) / EPB;           // 391 partition blocks (<=1024)

    // workspace layout (4-byte units)
    float* ws = (float*)d_ws;
    const size_t NP  = ((size_t)N + 255) & ~255ull;
    float* dinv = ws;                                   // NP
    unsigned short* bufHs  = (unsigned short*)(ws + NP);        // N*64 bf16
    unsigned short* bufAct = bufHs + (size_t)N * 64;            // N*64 bf16
    int*   rptr  = (int*)(bufAct + (size_t)N * 64);     // N
    int*   rdeg  = rptr + N;                            // N
    int*   btot  = rdeg + N;                            // NB2 (pad 256)
    int*   bh    = btot + 256;                          // NB2*nblk
    size_t bhsz  = ((size_t)NB2 * nblk + 1) & ~1ull;
    unsigned int* buf = (unsigned int*)(bh + bhsz);     // NB2*BUCKCAP
    int*   csr   = (int*)(buf + (size_t)NB2 * BUCKCAP); // NB2*BUCKCAP

    dim3 blk(BLK);
    int gRows = (N + 63) / 64;
    int gQW   = (N * 16 + BLK - 1) / BLK;    // quarter-wave per node

    // ---- binned partition -> CSR + degrees ----
    part_hist<<<nblk, blk, 0, stream>>>(dst, bh, E, nblk, NB2);
    part_scan<<<NB2, blk, 0, stream>>>(bh, btot, nblk);
    part_scatter<<<nblk, blk, 0, stream>>>(src, dst, bh, buf, E, nblk, NB2);
    csr_finalize<<<NB2, blk, 0, stream>>>(buf, btot, rptr, rdeg, dinv, csr, N);

    // ---- layer 1: 128 -> 64, relu ----
    gemm_mfma<128, 64, true><<<gRows, blk, 0, stream>>>(x, W1, dinv, bufHs, N);
    agg4<64, true, true, 64><<<gQW, blk, 0, stream>>>(bufHs, rptr, rdeg, csr, dinv, bb1, bufAct, N);

    // ---- layer 2: 64 -> 64, relu ----
    gemm_mfma<64, 64, false><<<gRows, blk, 0, stream>>>(bufAct, W2, dinv, bufHs, N);
    agg4<64, true, true, 64><<<gQW, blk, 0, stream>>>(bufHs, rptr, rdeg, csr, dinv, bb2, bufAct, N);

    // ---- layer 3: 64 -> 40 (bf16 rows zero-padded to 64), no relu ----
    gemm_mfma<64, 40, false><<<gRows, blk, 0, stream>>>(bufAct, W3, dinv, bufHs, N);
    agg4<40, false, false, 40><<<gQW, blk, 0, stream>>>(bufHs, rptr, rdeg, csr, dinv, bb3, out, N);
}

// Round 11
// 287.181 us; speedup vs baseline: 2.6845x; 1.0011x over previous
//
#include <hip/hip_runtime.h>
#include <hip/hip_bf16.h>

// GCN 3-layer. CSR via LDS-binned partition into fixed-capacity bucket
// windows. bf16 MFMA GEMM + bf16 gather (8-deep batched loads).
// Layer-3 hs packed at stride 40 (no pad fetch in the 40-dim gather).
// NOTE: round-10's degree-sorted perm REVERTED — it passed first-call
// validation but diverged on graph replays (state/timing-sensitive);
// direct node mapping (this version's structure) is replay-stable.

constexpr int BLK = 256;
constexpr int SB2 = 9;                  // bucket = 512 nodes
constexpr int EPB = 4096;               // edges per partition block
constexpr int BUCKCAP = 10240;          // bucket window capacity (mean 8192, +22 sigma)
// packed partition word: (local_node_id << 23) | src   (requires N < 2^23)

typedef __attribute__((ext_vector_type(8))) short bf16x8;   // 8 bf16 = 4 VGPR
typedef __attribute__((ext_vector_type(4))) float f32x4;    // MFMA acc

__device__ inline unsigned short bf_rne(float f) {
    unsigned int u = __float_as_uint(f);
    unsigned int r = (u + 0x7fffu + ((u >> 16) & 1u)) >> 16;
    return (unsigned short)r;
}
__device__ inline unsigned int pk(unsigned short lo, unsigned short hi) {
    return (unsigned int)lo | ((unsigned int)hi << 16);
}

// ---------- Pass A: per-block histogram of dst>>SB2 (int4 reads) ----------
__global__ __launch_bounds__(256) void part_hist(
    const int* __restrict__ dst, int* __restrict__ bh, int E, int nblk, int NB2) {
    __shared__ int lh[256];               // NB2 <= 256
    int k = blockIdx.x, t = threadIdx.x;
    lh[t] = 0;
    __syncthreads();
    const int4* dp = (const int4*)(dst + k * EPB);
#pragma unroll
    for (int j = 0; j < EPB / 1024; ++j) {
        int idx = j * 256 + t;            // int4 index within block
        int e = k * EPB + idx * 4;
        if (e < E) {                      // E % 4 == 0 -> whole int4 valid
            int4 d4 = dp[idx];
            atomicAdd(&lh[d4.x >> SB2], 1);
            atomicAdd(&lh[d4.y >> SB2], 1);
            atomicAdd(&lh[d4.z >> SB2], 1);
            atomicAdd(&lh[d4.w >> SB2], 1);
        }
    }
    __syncthreads();
    if (t < NB2) bh[t * nblk + k] = lh[t];
}

// ---------- Pass A': per bucket, exclusive scan over blocks; base = b*BUCKCAP ----------
__global__ __launch_bounds__(256) void part_scan(
    int* __restrict__ bh, int* __restrict__ btot, int nblk) {
    __shared__ int sh[256];
    int b = blockIdx.x, t = threadIdx.x;
    int base = b * BUCKCAP;
    int v[4]; int s = 0;                  // supports nblk <= 1024
#pragma unroll
    for (int j = 0; j < 4; ++j) {
        int idx = t * 4 + j;
        v[j] = (idx < nblk) ? bh[b * nblk + idx] : 0;
        s += v[j];
    }
    sh[t] = s;
    __syncthreads();
    for (int off = 1; off < 256; off <<= 1) {
        int x = (t >= off) ? sh[t - off] : 0;
        __syncthreads();
        sh[t] += x;
        __syncthreads();
    }
    int run = sh[t] - s;
    if (t == 255) btot[b] = (sh[255] < BUCKCAP) ? sh[255] : BUCKCAP;  // safety clamp
#pragma unroll
    for (int j = 0; j < 4; ++j) {
        int idx = t * 4 + j;
        if (idx < nblk) bh[b * nblk + idx] = base + run;
        run += v[j];
    }
}

// ---------- Pass B: scatter packed (local,src) into private (block,bucket) runs ----------
__global__ __launch_bounds__(256) void part_scatter(
    const int* __restrict__ src, const int* __restrict__ dst,
    const int* __restrict__ bh, unsigned int* __restrict__ buf,
    int E, int nblk, int NB2) {
    __shared__ int lbase[256];
    __shared__ int lcnt[256];
    int k = blockIdx.x, t = threadIdx.x;
    lcnt[t] = 0;
    if (t < NB2) lbase[t] = bh[t * nblk + k];
    __syncthreads();
    const int4* dp = (const int4*)(dst + k * EPB);
    const int4* sp = (const int4*)(src + k * EPB);
#pragma unroll
    for (int j = 0; j < EPB / 1024; ++j) {
        int idx = j * 256 + t;
        int e = k * EPB + idx * 4;
        if (e < E) {
            int4 d4 = dp[idx];
            int4 s4 = sp[idx];
            int d, bkt, p;
            d = d4.x; bkt = d >> SB2; p = lbase[bkt] + atomicAdd(&lcnt[bkt], 1);
            buf[p] = ((unsigned int)(d & 511) << 23) | (unsigned int)s4.x;
            d = d4.y; bkt = d >> SB2; p = lbase[bkt] + atomicAdd(&lcnt[bkt], 1);
            buf[p] = ((unsigned int)(d & 511) << 23) | (unsigned int)s4.y;
            d = d4.z; bkt = d >> SB2; p = lbase[bkt] + atomicAdd(&lcnt[bkt], 1);
            buf[p] = ((unsigned int)(d & 511) << 23) | (unsigned int)s4.z;
            d = d4.w; bkt = d >> SB2; p = lbase[bkt] + atomicAdd(&lcnt[bkt], 1);
            buf[p] = ((unsigned int)(d & 511) << 23) | (unsigned int)s4.w;
        }
    }
}

// ---------- Pass C: per bucket — node hist, scan, rptr/rdeg/dinv, csr scatter ----------
__global__ __launch_bounds__(256) void csr_finalize(
    const unsigned int* __restrict__ buf, const int* __restrict__ btot,
    int* __restrict__ rptr, int* __restrict__ rdeg, float* __restrict__ dinv,
    int* __restrict__ csr, int N) {
    __shared__ int hist[1 << SB2];        // 512
    __shared__ int excl[1 << SB2];
    __shared__ int ssc[256];
    int b = blockIdx.x, t = threadIdx.x;
    int nb0 = b << SB2;
    int nn = N - nb0; if (nn > (1 << SB2)) nn = 1 << SB2;
    int beg = b * BUCKCAP;
    int end = beg + btot[b];

    hist[t] = 0; hist[t + 256] = 0;
    __syncthreads();
    for (int i = beg + t; i < end; i += 256)
        atomicAdd(&hist[buf[i] >> 23], 1);
    __syncthreads();

    int a0 = hist[2 * t], a1 = hist[2 * t + 1];
    int s = a0 + a1;
    ssc[t] = s;
    __syncthreads();
    for (int off = 1; off < 256; off <<= 1) {
        int x = (t >= off) ? ssc[t - off] : 0;
        __syncthreads();
        ssc[t] += x;
        __syncthreads();
    }
    int run = ssc[t] - s;
    excl[2 * t] = run;
    excl[2 * t + 1] = run + a0;
    __syncthreads();

    for (int j = t; j < nn; j += 256) {
        rptr[nb0 + j] = beg + excl[j];
        rdeg[nb0 + j] = hist[j];
        dinv[nb0 + j] = rsqrtf((float)hist[j] + 1.0f);   // +1 self-loop
    }
    __syncthreads();

    hist[t] = 0; hist[t + 256] = 0;
    __syncthreads();
    for (int i = beg + t; i < end; i += 256) {
        unsigned int w = buf[i];
        int local = w >> 23;
        int p = beg + excl[local] + atomicAdd(&hist[local], 1);
        csr[p] = (int)(w & 0x7fffffu);
    }
}

// ---------- MFMA GEMM: hs(bf16, stride HSTRIDE) = (A @ W) * d_inv[row] ----------
template<int K, int NOUT, int HSTRIDE, bool AFP32>
__global__ __launch_bounds__(256) void gemm_mfma(
    const void* __restrict__ Aptr, const float* __restrict__ W,
    const float* __restrict__ d_inv, unsigned short* __restrict__ hs, int M)
{
    __shared__ unsigned short Wt[64][K + 8];   // [col][k], +8 pad: <=2-way LDS alias
    __shared__ float Cst[64][68];              // epilogue staging

    const int t = threadIdx.x;
    const int wave = t >> 6, lane = t & 63;
    const int m = lane & 15, kq = lane >> 4;

    for (int idx = t; idx < K * 64; idx += 256) {
        int k = idx >> 6, c = idx & 63;
        float wv = (c < NOUT) ? W[k * NOUT + c] : 0.0f;
        Wt[c][k] = bf_rne(wv);
    }
    __syncthreads();

    const int rb = blockIdx.x * 64;
    int arow = rb + wave * 16 + m;
    if (arow >= M) arow = M - 1;               // clamp (stores are guarded)

    f32x4 acc[4] = {{0.f,0.f,0.f,0.f},{0.f,0.f,0.f,0.f},
                    {0.f,0.f,0.f,0.f},{0.f,0.f,0.f,0.f}};
    union Frag { bf16x8 v; unsigned short u[8]; };

#pragma unroll
    for (int kc = 0; kc < K / 32; ++kc) {
        const int kbase = kc * 32 + kq * 8;
        Frag a;
        if (AFP32) {
            const float* ap = (const float*)Aptr + (size_t)arow * K + kbase;
            float4 x0 = *(const float4*)ap;
            float4 x1 = *(const float4*)(ap + 4);
            a.u[0] = bf_rne(x0.x); a.u[1] = bf_rne(x0.y);
            a.u[2] = bf_rne(x0.z); a.u[3] = bf_rne(x0.w);
            a.u[4] = bf_rne(x1.x); a.u[5] = bf_rne(x1.y);
            a.u[6] = bf_rne(x1.z); a.u[7] = bf_rne(x1.w);
        } else {
            const unsigned short* ap = (const unsigned short*)Aptr + (size_t)arow * 64 + kbase;
            a.v = *(const bf16x8*)ap;
        }
#pragma unroll
        for (int ct = 0; ct < 4; ++ct) {
            Frag b;
            b.v = *(const bf16x8*)(&Wt[ct * 16 + m][kbase]);
            acc[ct] = __builtin_amdgcn_mfma_f32_16x16x32_bf16(a.v, b.v, acc[ct], 0, 0, 0);
        }
    }

#pragma unroll
    for (int ct = 0; ct < 4; ++ct)
#pragma unroll
        for (int r = 0; r < 4; ++r)
            Cst[wave * 16 + kq * 4 + r][ct * 16 + m] = acc[ct][r];
    __syncthreads();

    int row = t >> 2, seg = t & 3;
    int grow = rb + row;
    int c0 = seg * 16;
    if (grow < M && c0 < NOUT) {
        float di = d_inv[grow];
        unsigned int uu[8];
#pragma unroll
        for (int j = 0; j < 8; ++j) {
            float v0 = Cst[row][c0 + 2 * j]     * di;
            float v1 = Cst[row][c0 + 2 * j + 1] * di;
            uu[j] = pk(bf_rne(v0), bf_rne(v1));
        }
        unsigned short* orow = hs + (size_t)grow * HSTRIDE + c0;
        *(uint4*)orow = make_uint4(uu[0], uu[1], uu[2], uu[3]);
        if (NOUT - c0 > 8)
            *((uint4*)orow + 1) = make_uint4(uu[4], uu[5], uu[6], uu[7]);
    }
}

// ---------- fused aggregate + epilogue: quarter-wave per node ----------
// lane = sub*16 + q. Lane owns dims [q*4, q*4+4): private accumulate, no
// reduce. Gather batched 8-deep: 8 independent loads in flight per lane.
template<int DACT, int HSTRIDE, bool RELU, bool OBF16, int OSTRIDE>
__global__ __launch_bounds__(256) void agg4(
    const unsigned short* __restrict__ hs, const int* __restrict__ rptr,
    const int* __restrict__ rdeg, const int* __restrict__ csr,
    const float* __restrict__ dinv, const float* __restrict__ b,
    void* __restrict__ out, int N)
{
    int i = (blockIdx.x * 256 + threadIdx.x) >> 4;     // node per quarter-wave
    if (i >= N) return;
    int lane = threadIdx.x & 63;
    int q  = lane & 15;                                 // dim quad
    int sb = lane & 48;                                 // subgroup base lane
    constexpr int QACT = DACT / 4;                      // active quads (16 or 10)
    const bool act = (q < QACT);

    int beg = rptr[i];
    int end = beg + rdeg[i];

    float a0 = 0.f, a1 = 0.f, a2 = 0.f, a3 = 0.f;
    if (act) {                                          // self-loop init
        uint2 u0 = *(const uint2*)(hs + (size_t)i * HSTRIDE + q * 4);
        a0 = __uint_as_float(u0.x << 16);
        a1 = __uint_as_float(u0.x & 0xffff0000u);
        a2 = __uint_as_float(u0.y << 16);
        a3 = __uint_as_float(u0.y & 0xffff0000u);
    }

    for (int c = beg; c < end; c += 16) {
        int s_l = (c + q < end) ? csr[c + q] : 0;      // coalesced 64B prefetch
        int m = end - c; if (m > 16) m = 16;
        int k = 0;
        for (; k + 8 <= m; k += 8) {                   // 8 loads in flight
            int ss[8];
#pragma unroll
            for (int j = 0; j < 8; ++j) ss[j] = __shfl(s_l, sb | (k + j), 64);
            if (act) {
                uint2 vv[8];
#pragma unroll
                for (int j = 0; j < 8; ++j)
                    vv[j] = *(const uint2*)(hs + (size_t)ss[j] * HSTRIDE + q * 4);
#pragma unroll
                for (int j = 0; j < 8; ++j) {
                    a0 += __uint_as_float(vv[j].x << 16);
                    a1 += __uint_as_float(vv[j].x & 0xffff0000u);
                    a2 += __uint_as_float(vv[j].y << 16);
                    a3 += __uint_as_float(vv[j].y & 0xffff0000u);
                }
            }
        }
        for (; k < m; ++k) {
            int s = __shfl(s_l, sb | k, 64);
            if (act) {
                uint2 u = *(const uint2*)(hs + (size_t)s * HSTRIDE + q * 4);
                a0 += __uint_as_float(u.x << 16);
                a1 += __uint_as_float(u.x & 0xffff0000u);
                a2 += __uint_as_float(u.y << 16);
                a3 += __uint_as_float(u.y & 0xffff0000u);
            }
        }
    }

    if (act) {
        float di = dinv[i];
        const float4 bv = *(const float4*)(b + q * 4);
        a0 = di * a0 + bv.x; a1 = di * a1 + bv.y;
        a2 = di * a2 + bv.z; a3 = di * a3 + bv.w;
        if (RELU) {
            a0 = fmaxf(a0, 0.f); a1 = fmaxf(a1, 0.f);
            a2 = fmaxf(a2, 0.f); a3 = fmaxf(a3, 0.f);
        }
        if (OBF16) {
            unsigned short* ob = (unsigned short*)out;
            uint2 o;
            o.x = pk(bf_rne(a0), bf_rne(a1));
            o.y = pk(bf_rne(a2), bf_rne(a3));
            *(uint2*)(ob + (size_t)i * 64 + q * 4) = o;
        } else {
            float* of = (float*)out;
            *(float4*)(of + (size_t)i * OSTRIDE + q * 4) = make_float4(a0, a1, a2, a3);
        }
    }
}

extern "C" void kernel_launch(void* const* d_in, const int* in_sizes, int n_in,
                              void* d_out, int out_size, void* d_ws, size_t ws_size,
                              hipStream_t stream) {
    const float* x   = (const float*)d_in[0];
    const int*   ei  = (const int*)  d_in[1];
    const float* W1  = (const float*)d_in[2];
    const float* bb1 = (const float*)d_in[3];
    const float* W2  = (const float*)d_in[4];
    const float* bb2 = (const float*)d_in[5];
    const float* W3  = (const float*)d_in[6];
    const float* bb3 = (const float*)d_in[7];
    float* out = (float*)d_out;

    const int N = in_sizes[0] / 128;      // 100000
    const int E = in_sizes[1] / 2;        // 1600000
    const int* src = ei;
    const int* dst = ei + E;
    const int NB2  = (N + (1 << SB2) - 1) >> SB2;   // 196 buckets (<=256)
    const int nblk = (E + EPB - 1) / EPB;           // 391 partition blocks (<=1024)

    // workspace layout (4-byte units)
    float* ws = (float*)d_ws;
    const size_t NP  = ((size_t)N + 255) & ~255ull;
    float* dinv = ws;                                   // NP
    unsigned short* bufHs  = (unsigned short*)(ws + NP);        // N*64 bf16
    unsigned short* bufAct = bufHs + (size_t)N * 64;            // N*64 bf16
    int*   rptr  = (int*)(bufAct + (size_t)N * 64);     // N
    int*   rdeg  = rptr + N;                            // N
    int*   btot  = rdeg + N;                            // NB2 (pad 256)
    int*   bh    = btot + 256;                          // NB2*nblk
    size_t bhsz  = ((size_t)NB2 * nblk + 1) & ~1ull;
    unsigned int* buf = (unsigned int*)(bh + bhsz);     // NB2*BUCKCAP
    int*   csr   = (int*)(buf + (size_t)NB2 * BUCKCAP); // NB2*BUCKCAP

    dim3 blk(BLK);
    int gRows = (N + 63) / 64;
    int gQW   = (N * 16 + BLK - 1) / BLK;    // quarter-wave per node

    // ---- binned partition -> CSR + degrees ----
    part_hist<<<nblk, blk, 0, stream>>>(dst, bh, E, nblk, NB2);
    part_scan<<<NB2, blk, 0, stream>>>(bh, btot, nblk);
    part_scatter<<<nblk, blk, 0, stream>>>(src, dst, bh, buf, E, nblk, NB2);
    csr_finalize<<<NB2, blk, 0, stream>>>(buf, btot, rptr, rdeg, dinv, csr, N);

    // ---- layer 1: 128 -> 64, relu ----
    gemm_mfma<128, 64, 64, true><<<gRows, blk, 0, stream>>>(x, W1, dinv, bufHs, N);
    agg4<64, 64, true, true, 64><<<gQW, blk, 0, stream>>>(bufHs, rptr, rdeg, csr, dinv, bb1, bufAct, N);

    // ---- layer 2: 64 -> 64, relu ----
    gemm_mfma<64, 64, 64, false><<<gRows, blk, 0, stream>>>(bufAct, W2, dinv, bufHs, N);
    agg4<64, 64, true, true, 64><<<gQW, blk, 0, stream>>>(bufHs, rptr, rdeg, csr, dinv, bb2, bufAct, N);

    // ---- layer 3: 64 -> 40 packed stride-40, no relu ----
    gemm_mfma<64, 40, 40, false><<<gRows, blk, 0, stream>>>(bufAct, W3, dinv, bufHs, N);
    agg4<40, 40, false, false, 40><<<gQW, blk, 0, stream>>>(bufHs, rptr, rdeg, csr, dinv, bb3, out, N);
}